// Round 4
// baseline (335.881 us; speedup 1.0000x reference)
//
#include <hip/hip_runtime.h>
#include <cstdint>
#include <cstddef>

#define DEVINL __device__ __forceinline__

typedef short short8 __attribute__((ext_vector_type(8)));
typedef float f32x4 __attribute__((ext_vector_type(4)));
typedef unsigned short ushort;
typedef ushort u16x8 __attribute__((ext_vector_type(8)));
typedef ushort u16x4 __attribute__((ext_vector_type(4)));

DEVINL float bf2f(ushort u) {
  union { unsigned int i; float f; } v; v.i = ((unsigned int)u) << 16; return v.f;
}
DEVINL ushort f2bf(float f) {
  union { float f; unsigned int i; } v; v.f = f;
  unsigned int u = v.i;
  unsigned int r = u + 0x7fffu + ((u >> 16) & 1u);
  return (ushort)(r >> 16);
}
// Diagnostic clamp (fmax/fmin drop quiet NaN): should never engage now.
DEVINL float scrub(float f, float lim) { return fminf(fmaxf(f, -lim), lim); }

// ------- weight transpose + fp32->bf16 cast: in f32 [R,C] -> out bf16 [C,R] ----
__global__ void transpose_k(const float* __restrict__ in, ushort* __restrict__ out,
                            int R, int C) {
  __shared__ float tile[32][33];
  int bx = blockIdx.x, by = blockIdx.y;
  int tx = threadIdx.x, ty = threadIdx.y;  // (32,8)
  int x = bx * 32 + tx;
#pragma unroll
  for (int i = 0; i < 4; i++) {
    int y = by * 32 + ty + i * 8;
    tile[ty + i * 8][tx] = in[(size_t)y * C + x];
  }
  __syncthreads();
  int x2 = by * 32 + tx;
#pragma unroll
  for (int i = 0; i < 4; i++) {
    int y2 = bx * 32 + ty + i * 8;
    out[(size_t)y2 * R + x2] = f2bf(tile[tx][ty + i * 8]);
  }
}

// ------- LayerNorm: wave per row of 384; fp32 in -> bf16 out ----
__global__ __launch_bounds__(256) void ln_k(const float* __restrict__ x,
                                            const float* __restrict__ g,
                                            const float* __restrict__ b,
                                            ushort* __restrict__ out) {
  int wave = threadIdx.x >> 6;
  int lane = threadIdx.x & 63;
  int row = blockIdx.x * 4 + wave;
  const float* xr = x + (size_t)row * 384;
  float v[6];
#pragma unroll
  for (int j = 0; j < 3; j++) {
    float2 p = *(const float2*)(xr + lane * 2 + j * 128);
    v[2 * j] = scrub(p.x, 1e4f);
    v[2 * j + 1] = scrub(p.y, 1e4f);
  }
  float s = v[0] + v[1] + v[2] + v[3] + v[4] + v[5];
#pragma unroll
  for (int off = 32; off; off >>= 1) s += __shfl_xor(s, off);
  float mu = s * (1.0f / 384.0f);
  float s2 = 0.f;
#pragma unroll
  for (int j = 0; j < 6; j++) { float d = v[j] - mu; s2 += d * d; }
#pragma unroll
  for (int off = 32; off; off >>= 1) s2 += __shfl_xor(s2, off);
  float rs = rsqrtf(s2 * (1.0f / 384.0f) + 1e-5f);
  ushort* orow = out + (size_t)row * 384;
#pragma unroll
  for (int j = 0; j < 3; j++) {
    int c = lane * 2 + j * 128;
    float2 pg = *(const float2*)(g + c);
    float2 pb = *(const float2*)(b + c);
    float y0 = (v[2 * j] - mu) * rs * pg.x + pb.x;
    float y1 = (v[2 * j + 1] - mu) * rs * pg.y + pb.y;
    uint32_t po = (uint32_t)f2bf(y0) | ((uint32_t)f2bf(y1) << 16);
    *(uint32_t*)(orow + c) = po;
  }
}

// ------- GEMM: C[M,N] = A[M,K](bf16) @ W[K,N], W as bf16 WT[N,K] ----
// MODE 0: QKV — grid.z selects Wq/Wk/Wv; q,k -> [B,H,T,D] bf16; v -> [B,H,D,T] bf16
// MODE 1: outf = A@W + bias + residf (all fp32 epilogue, ld 384) [proj->xr, ff2]
// MODE 2: outa = bf16(relu(A@W + bias)) (ld 1536)                [ff1]
template <int MODE>
__global__ __launch_bounds__(256) void gemm_k(
    const ushort* __restrict__ A, int K,
    const ushort* __restrict__ WTa, const ushort* __restrict__ WTb,
    const ushort* __restrict__ WTc,
    const float* __restrict__ bias, const float* residf,
    ushort* __restrict__ outa, ushort* __restrict__ outb,
    ushort* __restrict__ outc, float* outf) {
  __shared__ ushort As[128][40];
  __shared__ ushort Bs[128][40];
  int tid = threadIdx.x;
  int lane = tid & 63, wave = tid >> 6;
  int wm = wave & 1, wn = wave >> 1;
  int q4 = lane >> 4, ln16 = lane & 15;
  int rowBase = blockIdx.x * 128;
  int colBase = blockIdx.y * 128;

  const ushort* WT;
  if (MODE == 0) {
    int z = blockIdx.z;
    WT = (z == 0) ? WTa : (z == 1) ? WTb : WTc;
  } else {
    WT = WTa;
  }

  f32x4 acc[4][4];
#pragma unroll
  for (int i = 0; i < 4; i++)
#pragma unroll
    for (int j = 0; j < 4; j++) acc[i][j] = (f32x4){0.f, 0.f, 0.f, 0.f};

  int sRow = tid >> 2;
  int sKg = (tid & 3) * 8;

  for (int kb = 0; kb < K; kb += 32) {
#pragma unroll
    for (int r2 = 0; r2 < 128; r2 += 64) {
      int row = sRow + r2;
      *(u16x8*)&As[row][sKg] = *(const u16x8*)&A[(size_t)(rowBase + row) * K + kb + sKg];
      *(u16x8*)&Bs[row][sKg] = *(const u16x8*)&WT[(size_t)(colBase + row) * K + kb + sKg];
    }
    __syncthreads();
    short8 af[4], bfr[4];
#pragma unroll
    for (int i = 0; i < 4; i++) af[i] = *(const short8*)&As[wm * 64 + i * 16 + ln16][q4 * 8];
#pragma unroll
    for (int j = 0; j < 4; j++) bfr[j] = *(const short8*)&Bs[wn * 64 + j * 16 + ln16][q4 * 8];
#pragma unroll
    for (int i = 0; i < 4; i++)
#pragma unroll
      for (int j = 0; j < 4; j++)
        acc[i][j] = __builtin_amdgcn_mfma_f32_16x16x32_bf16(af[i], bfr[j], acc[i][j], 0, 0, 0);
    __syncthreads();
  }

#pragma unroll
  for (int i = 0; i < 4; i++) {
#pragma unroll
    for (int j = 0; j < 4; j++) {
      int row0 = rowBase + wm * 64 + i * 16 + q4 * 4;
      int col = colBase + wn * 64 + j * 16 + ln16;
      if (MODE == 0) {
        int z = blockIdx.z;
        if (z < 2) {
          ushort* o = (z == 0) ? outa : outb;
#pragma unroll
          for (int r = 0; r < 4; r++) {
            int row = row0 + r;
            int bb = row >> 9, t = row & 511, h = col >> 6, d = col & 63;
            o[(((size_t)(bb * 6 + h) * 512) + t) * 64 + d] = f2bf(scrub(acc[i][j][r], 1e4f));
          }
        } else {
          int bb = row0 >> 9, t0 = row0 & 511, h = col >> 6, d = col & 63;
          u16x4 pk = {f2bf(scrub(acc[i][j][0], 1e4f)), f2bf(scrub(acc[i][j][1], 1e4f)),
                      f2bf(scrub(acc[i][j][2], 1e4f)), f2bf(scrub(acc[i][j][3], 1e4f))};
          *(u16x4*)&outc[(((size_t)(bb * 6 + h) * 64) + d) * 512 + t0] = pk;
        }
      } else if (MODE == 1) {
        float bcol = bias[col];
#pragma unroll
        for (int r = 0; r < 4; r++) {
          size_t idx = (size_t)(row0 + r) * 384 + col;
          outf[idx] = scrub(acc[i][j][r] + bcol + residf[idx], 1e4f);
        }
      } else {
        float bcol = bias[col];
#pragma unroll
        for (int r = 0; r < 4; r++) {
          size_t idx = (size_t)(row0 + r) * 1536 + col;
          float vv = scrub(acc[i][j][r] + bcol, 1e4f);
          outa[idx] = f2bf(vv > 0.f ? vv : 0.f);
        }
      }
    }
  }
}

// ------- flash attention: wave = 16 q rows, 32-key tiles (all bf16 in/out) ----
__global__ __launch_bounds__(256) void attn_k(const ushort* __restrict__ qg,
                                              const ushort* __restrict__ kg,
                                              const ushort* __restrict__ vtg,
                                              ushort* __restrict__ outg) {
  __shared__ ushort Ks[32][88];
  __shared__ ushort VTs[64][40];
  __shared__ ushort Pw[4][16][48];
  int tid = threadIdx.x, lane = tid & 63, wave = tid >> 6;
  int qb = blockIdx.x;   // 0..7
  int bh = blockIdx.y;   // 0..191
  int q4 = lane >> 4, ln16 = lane & 15;
  int q0 = qb * 64 + wave * 16;

  const ushort* qp = qg + (size_t)bh * 512 * 64;
  const ushort* kp = kg + (size_t)bh * 512 * 64;
  const ushort* vp = vtg + (size_t)bh * 64 * 512;

  short8 aq0 = *(const short8*)&qp[(size_t)(q0 + ln16) * 64 + q4 * 8];
  short8 aq1 = *(const short8*)&qp[(size_t)(q0 + ln16) * 64 + 32 + q4 * 8];

  f32x4 O[4];
#pragma unroll
  for (int j = 0; j < 4; j++) O[j] = (f32x4){0.f, 0.f, 0.f, 0.f};
  float m_[4], l_[4];
#pragma unroll
  for (int r = 0; r < 4; r++) { m_[r] = -3.0e38f; l_[r] = 0.f; }

  int sEnd = qb * 64 + 64;
  for (int s0 = 0; s0 < sEnd; s0 += 32) {
    {
      int s = tid >> 3, dg = (tid & 7) * 8;
      *(u16x8*)&Ks[s][dg] = *(const u16x8*)&kp[(size_t)(s0 + s) * 64 + dg];
      int d = tid >> 2, sg = (tid & 3) * 8;
      *(u16x8*)&VTs[d][sg] = *(const u16x8*)&vp[(size_t)d * 512 + s0 + sg];
    }
    __syncthreads();
    if (s0 <= q0 + 15) {
      f32x4 S[2];
#pragma unroll
      for (int sub = 0; sub < 2; sub++) {
        short8 kb0 = *(const short8*)&Ks[sub * 16 + ln16][q4 * 8];
        short8 kb1 = *(const short8*)&Ks[sub * 16 + ln16][32 + q4 * 8];
        f32x4 z = (f32x4){0.f, 0.f, 0.f, 0.f};
        z = __builtin_amdgcn_mfma_f32_16x16x32_bf16(aq0, kb0, z, 0, 0, 0);
        z = __builtin_amdgcn_mfma_f32_16x16x32_bf16(aq1, kb1, z, 0, 0, 0);
        S[sub] = z;
      }
#pragma unroll
      for (int sub = 0; sub < 2; sub++)
#pragma unroll
        for (int r = 0; r < 4; r++) {
          int t = q0 + q4 * 4 + r;
          int s = s0 + sub * 16 + ln16;
          float vv = scrub(S[sub][r], 1e30f) * 0.125f;
          S[sub][r] = (s <= t) ? vv : -3.0e38f;
        }
      float alpha[4];
#pragma unroll
      for (int r = 0; r < 4; r++) {
        float vm = fmaxf(S[0][r], S[1][r]);
#pragma unroll
        for (int off = 1; off < 16; off <<= 1) vm = fmaxf(vm, __shfl_xor(vm, off));
        float mn = fmaxf(m_[r], vm);
        alpha[r] = __expf(m_[r] - mn);
        m_[r] = mn;
        float p0 = __expf(S[0][r] - mn);
        float p1 = __expf(S[1][r] - mn);
        S[0][r] = p0; S[1][r] = p1;
        float ps = p0 + p1;
#pragma unroll
        for (int off = 1; off < 16; off <<= 1) ps += __shfl_xor(ps, off);
        l_[r] = l_[r] * alpha[r] + ps;
      }
#pragma unroll
      for (int j = 0; j < 4; j++)
#pragma unroll
        for (int r = 0; r < 4; r++) O[j][r] *= alpha[r];
#pragma unroll
      for (int sub = 0; sub < 2; sub++)
#pragma unroll
        for (int r = 0; r < 4; r++)
          Pw[wave][q4 * 4 + r][sub * 16 + ln16] = f2bf(S[sub][r]);
      asm volatile("" ::: "memory");  // forbid hoisting Pw read above writes
      union { u16x8 u; short8 s; } pu;
      pu.u = *(const u16x8*)&Pw[wave][ln16][q4 * 8];
      short8 pa = pu.s;
#pragma unroll
      for (int j = 0; j < 4; j++) {
        short8 vb = *(const short8*)&VTs[j * 16 + ln16][q4 * 8];
        O[j] = __builtin_amdgcn_mfma_f32_16x16x32_bf16(pa, vb, O[j], 0, 0, 0);
      }
    }
    __syncthreads();
  }

  int b = bh / 6, h = bh % 6;
#pragma unroll
  for (int r = 0; r < 4; r++) {
    float inv = 1.0f / l_[r];
    int t = q0 + q4 * 4 + r;
    size_t base = ((size_t)(b * 512) + t) * 384 + h * 64;
#pragma unroll
    for (int j = 0; j < 4; j++)
      outg[base + j * 16 + ln16] = f2bf(scrub(O[j][r] * inv, 1e4f));
  }
}

// ---------------- host ----------------
extern "C" void kernel_launch(void* const* d_in, const int* in_sizes, int n_in,
                              void* d_out, int out_size, void* d_ws, size_t ws_size,
                              hipStream_t stream) {
  const float* x = (const float*)d_in[0];
  const float* Wq = (const float*)d_in[1];
  const float* Wk = (const float*)d_in[2];
  const float* Wv = (const float*)d_in[3];
  const float* Wp = (const float*)d_in[4];
  const float* bp = (const float*)d_in[5];
  const float* g1 = (const float*)d_in[6];
  const float* b1 = (const float*)d_in[7];
  const float* g2 = (const float*)d_in[8];
  const float* b2 = (const float*)d_in[9];
  const float* W1 = (const float*)d_in[10];
  const float* bf1 = (const float*)d_in[11];
  const float* W2 = (const float*)d_in[12];
  const float* bf2 = (const float*)d_in[13];
  float* outp = (float*)d_out;   // fp32 output; also hosts xr between proj and ff2

  char* ws = (char*)d_ws;
  size_t off = 0;
  auto alloc = [&](size_t elems) {
    ushort* p = (ushort*)(ws + off);
    off += elems * 2;
    return p;
  };
  ushort* WqT = alloc((size_t)384 * 384);
  ushort* WkT = alloc((size_t)384 * 384);
  ushort* WvT = alloc((size_t)384 * 384);
  ushort* WpT = alloc((size_t)384 * 384);
  ushort* W1T = alloc((size_t)384 * 1536);
  ushort* W2T = alloc((size_t)1536 * 384);
  ushort* bufq = alloc((size_t)16384 * 384);   // q, later h2
  ushort* m1 = alloc((size_t)16384 * 1536);    // [h1/attn | k | vT | spare] then ff1 out
  ushort* h1_attn = m1;
  ushort* bufk = m1 + (size_t)16384 * 384;
  ushort* vT = m1 + (size_t)2 * 16384 * 384;
  // total ws: ~66.5 MB

  dim3 tb(32, 8);
  transpose_k<<<dim3(12, 12), tb, 0, stream>>>(Wq, WqT, 384, 384);
  transpose_k<<<dim3(12, 12), tb, 0, stream>>>(Wk, WkT, 384, 384);
  transpose_k<<<dim3(12, 12), tb, 0, stream>>>(Wv, WvT, 384, 384);
  transpose_k<<<dim3(12, 12), tb, 0, stream>>>(Wp, WpT, 384, 384);
  transpose_k<<<dim3(48, 12), tb, 0, stream>>>(W1, W1T, 384, 1536);
  transpose_k<<<dim3(12, 48), tb, 0, stream>>>(W2, W2T, 1536, 384);

  // h1 = ln(x, g1, b1)  [fp32 -> bf16]
  ln_k<<<4096, 256, 0, stream>>>(x, g1, b1, h1_attn);
  // q,k,vT (bf16)
  gemm_k<0><<<dim3(128, 3, 3), 256, 0, stream>>>(h1_attn, 384, WqT, WkT, WvT,
                                                 nullptr, nullptr, bufq, bufk, vT, nullptr);
  // attention -> attn (bf16, overwrites h1 slot)
  attn_k<<<dim3(8, 192), 256, 0, stream>>>(bufq, bufk, vT, h1_attn);
  // xr = attn@Wp + bp + x  (fp32, into d_out)
  gemm_k<1><<<dim3(128, 3), 256, 0, stream>>>(h1_attn, 384, WpT, nullptr, nullptr,
                                              bp, x, nullptr, nullptr, nullptr, outp);
  // h2 = ln(xr, g2, b2)  [fp32 -> bf16, into q slot]
  ln_k<<<4096, 256, 0, stream>>>(outp, g2, b2, bufq);
  // m1 = relu(h2@W1 + bf1)  (bf16)
  gemm_k<2><<<dim3(128, 12), 256, 0, stream>>>(bufq, 384, W1T, nullptr, nullptr,
                                               bf1, nullptr, m1, nullptr, nullptr, nullptr);
  // out = m1@W2 + bf2 + xr  (fp32, in-place on d_out)
  gemm_k<1><<<dim3(128, 3), 256, 0, stream>>>(m1, 1536, W2T, nullptr, nullptr,
                                              bf2, outp, nullptr, nullptr, nullptr, outp);
}

// Round 5
// 295.417 us; speedup vs baseline: 1.1370x; 1.1370x over previous
//
#include <hip/hip_runtime.h>
#include <cstdint>
#include <cstddef>

#define DEVINL __device__ __forceinline__

typedef short short8 __attribute__((ext_vector_type(8)));
typedef float f32x4 __attribute__((ext_vector_type(4)));
typedef unsigned short ushort;
typedef ushort u16x8 __attribute__((ext_vector_type(8)));
typedef ushort u16x4 __attribute__((ext_vector_type(4)));

DEVINL float bf2f(ushort u) {
  union { unsigned int i; float f; } v; v.i = ((unsigned int)u) << 16; return v.f;
}
DEVINL ushort f2bf(float f) {
  union { float f; unsigned int i; } v; v.f = f;
  unsigned int u = v.i;
  unsigned int r = u + 0x7fffu + ((u >> 16) & 1u);
  return (ushort)(r >> 16);
}

// ------- weight transpose + fp32->bf16 cast: in f32 [R,C] -> out bf16 [C,R] ----
__global__ void transpose_k(const float* __restrict__ in, ushort* __restrict__ out,
                            int R, int C) {
  __shared__ float tile[32][33];
  int bx = blockIdx.x, by = blockIdx.y;
  int tx = threadIdx.x, ty = threadIdx.y;  // (32,8)
  int x = bx * 32 + tx;
#pragma unroll
  for (int i = 0; i < 4; i++) {
    int y = by * 32 + ty + i * 8;
    tile[ty + i * 8][tx] = in[(size_t)y * C + x];
  }
  __syncthreads();
  int x2 = by * 32 + tx;
#pragma unroll
  for (int i = 0; i < 4; i++) {
    int y2 = bx * 32 + ty + i * 8;
    out[(size_t)y2 * R + x2] = f2bf(tile[tx][ty + i * 8]);
  }
}

// ------- LayerNorm: wave per row of 384; fp32 in -> bf16 out ----
__global__ __launch_bounds__(256) void ln_k(const float* __restrict__ x,
                                            const float* __restrict__ g,
                                            const float* __restrict__ b,
                                            ushort* __restrict__ out) {
  int wave = threadIdx.x >> 6;
  int lane = threadIdx.x & 63;
  int row = blockIdx.x * 4 + wave;
  const float* xr = x + (size_t)row * 384;
  float v[6];
#pragma unroll
  for (int j = 0; j < 3; j++) {
    float2 p = *(const float2*)(xr + lane * 2 + j * 128);
    v[2 * j] = p.x;
    v[2 * j + 1] = p.y;
  }
  float s = v[0] + v[1] + v[2] + v[3] + v[4] + v[5];
#pragma unroll
  for (int off = 32; off; off >>= 1) s += __shfl_xor(s, off);
  float mu = s * (1.0f / 384.0f);
  float s2 = 0.f;
#pragma unroll
  for (int j = 0; j < 6; j++) { float d = v[j] - mu; s2 += d * d; }
#pragma unroll
  for (int off = 32; off; off >>= 1) s2 += __shfl_xor(s2, off);
  float rs = rsqrtf(s2 * (1.0f / 384.0f) + 1e-5f);
  ushort* orow = out + (size_t)row * 384;
#pragma unroll
  for (int j = 0; j < 3; j++) {
    int c = lane * 2 + j * 128;
    float2 pg = *(const float2*)(g + c);
    float2 pb = *(const float2*)(b + c);
    float y0 = (v[2 * j] - mu) * rs * pg.x + pb.x;
    float y1 = (v[2 * j + 1] - mu) * rs * pg.y + pb.y;
    uint32_t po = (uint32_t)f2bf(y0) | ((uint32_t)f2bf(y1) << 16);
    *(uint32_t*)(orow + c) = po;
  }
}

// ------- GEMM: C[M,N] = A[M,K](bf16) @ W[K,N], W as bf16 WT[N,K] ----
// MODE 0 (TN=128): QKV — grid.z selects Wq/Wk/Wv; q,k -> [B,H,T,D]; v -> [B,H,D,T]
// MODE 1 (TN=64):  outf = A@W + bias + residf (fp32 epilogue, ld 384) [proj, ff2]
// MODE 2 (TN=128): outa = bf16(relu(A@W + bias)) (ld 1536)            [ff1]
template <int MODE, int TN>
__global__ __launch_bounds__(256) void gemm_k(
    const ushort* __restrict__ A, int K,
    const ushort* __restrict__ WTa, const ushort* __restrict__ WTb,
    const ushort* __restrict__ WTc,
    const float* __restrict__ bias, const float* residf,
    ushort* __restrict__ outa, ushort* __restrict__ outb,
    ushort* __restrict__ outc, float* outf) {
  constexpr int NJ = TN / 32;  // 16-col acc tiles per wave
  __shared__ ushort As[128][40];
  __shared__ ushort Bs[TN][40];
  int tid = threadIdx.x;
  int lane = tid & 63, wave = tid >> 6;
  int wm = wave & 1, wn = wave >> 1;
  int q4 = lane >> 4, ln16 = lane & 15;
  int rowBase = blockIdx.x * 128;
  int colBase = blockIdx.y * TN;

  const ushort* WT;
  if (MODE == 0) {
    int z = blockIdx.z;
    WT = (z == 0) ? WTa : (z == 1) ? WTb : WTc;
  } else {
    WT = WTa;
  }

  f32x4 acc[4][NJ];
#pragma unroll
  for (int i = 0; i < 4; i++)
#pragma unroll
    for (int j = 0; j < NJ; j++) acc[i][j] = (f32x4){0.f, 0.f, 0.f, 0.f};

  int sRow = tid >> 2;
  int sKg = (tid & 3) * 8;

  for (int kb = 0; kb < K; kb += 32) {
#pragma unroll
    for (int r2 = 0; r2 < 128; r2 += 64) {
      int row = sRow + r2;
      *(u16x8*)&As[row][sKg] = *(const u16x8*)&A[(size_t)(rowBase + row) * K + kb + sKg];
    }
#pragma unroll
    for (int r2 = 0; r2 < TN; r2 += 64) {
      int row = sRow + r2;
      *(u16x8*)&Bs[row][sKg] = *(const u16x8*)&WT[(size_t)(colBase + row) * K + kb + sKg];
    }
    __syncthreads();
    short8 af[4], bfr[NJ];
#pragma unroll
    for (int i = 0; i < 4; i++) af[i] = *(const short8*)&As[wm * 64 + i * 16 + ln16][q4 * 8];
#pragma unroll
    for (int j = 0; j < NJ; j++)
      bfr[j] = *(const short8*)&Bs[wn * (TN / 2) + j * 16 + ln16][q4 * 8];
#pragma unroll
    for (int i = 0; i < 4; i++)
#pragma unroll
      for (int j = 0; j < NJ; j++)
        acc[i][j] = __builtin_amdgcn_mfma_f32_16x16x32_bf16(af[i], bfr[j], acc[i][j], 0, 0, 0);
    __syncthreads();
  }

#pragma unroll
  for (int i = 0; i < 4; i++) {
#pragma unroll
    for (int j = 0; j < NJ; j++) {
      int row0 = rowBase + wm * 64 + i * 16 + q4 * 4;
      int col = colBase + wn * (TN / 2) + j * 16 + ln16;
      if (MODE == 0) {
        int z = blockIdx.z;
        if (z < 2) {
          ushort* o = (z == 0) ? outa : outb;
#pragma unroll
          for (int r = 0; r < 4; r++) {
            int row = row0 + r;
            int bb = row >> 9, t = row & 511, h = col >> 6, d = col & 63;
            o[(((size_t)(bb * 6 + h) * 512) + t) * 64 + d] = f2bf(acc[i][j][r]);
          }
        } else {
          int bb = row0 >> 9, t0 = row0 & 511, h = col >> 6, d = col & 63;
          u16x4 pk = {f2bf(acc[i][j][0]), f2bf(acc[i][j][1]), f2bf(acc[i][j][2]),
                      f2bf(acc[i][j][3])};
          *(u16x4*)&outc[(((size_t)(bb * 6 + h) * 64) + d) * 512 + t0] = pk;
        }
      } else if (MODE == 1) {
        float bcol = bias[col];
#pragma unroll
        for (int r = 0; r < 4; r++) {
          size_t idx = (size_t)(row0 + r) * 384 + col;
          outf[idx] = acc[i][j][r] + bcol + residf[idx];
        }
      } else {
        float bcol = bias[col];
#pragma unroll
        for (int r = 0; r < 4; r++) {
          size_t idx = (size_t)(row0 + r) * 1536 + col;
          float vv = acc[i][j][r] + bcol;
          outa[idx] = f2bf(vv > 0.f ? vv : 0.f);
        }
      }
    }
  }
}

// ------- flash attention, S^T formulation: wave = 16 q rows, 64-key tiles ----
// S^T = K·Q^T (C layout: col=q=lane&15, row=key) -> softmax reductions are
// in-register + 2 shuffles; O^T = V^T·P^T accumulated in C layout (col=q, row=d).
// q,k: [B,H,T,D] bf16; vT: [B,H,D,T] bf16; out: [B,T,384] bf16.
__global__ __launch_bounds__(256) void attn_k(const ushort* __restrict__ qg,
                                              const ushort* __restrict__ kg,
                                              const ushort* __restrict__ vtg,
                                              ushort* __restrict__ outg) {
  __shared__ ushort Ks[64][88];   // [key][d]   176B rows: 16B-aligned b128
  __shared__ ushort VTs[64][88];  // [d][key]
  __shared__ ushort Pw[4][16][88];  // per-wave P^T staged as [q][key]
  int tid = threadIdx.x, lane = tid & 63, wave = tid >> 6;
  int qb = blockIdx.x;   // 0..7
  int bh = blockIdx.y;   // 0..191
  int quad = lane >> 4, ln16 = lane & 15;
  int q0 = qb * 64 + wave * 16;
  int t_row = q0 + ln16;  // this lane's absolute query index

  const ushort* qp = qg + (size_t)bh * 512 * 64;
  const ushort* kp = kg + (size_t)bh * 512 * 64;
  const ushort* vp = vtg + (size_t)bh * 64 * 512;

  // Q as B-operand: lane n=ln16 holds Q[n][quad*8+j] (d-chunks 0..31, 32..63)
  short8 bq0 = *(const short8*)&qp[(size_t)t_row * 64 + quad * 8];
  short8 bq1 = *(const short8*)&qp[(size_t)t_row * 64 + 32 + quad * 8];

  f32x4 O[4];  // O^T d-tiles: col=q=ln16, row=d=dt*16+quad*4+r
#pragma unroll
  for (int dt = 0; dt < 4; dt++) O[dt] = (f32x4){0.f, 0.f, 0.f, 0.f};
  float m_ = -3.0e38f, l_ = 0.f;  // per-lane (q), replicated across quads

  const float SC = 0.125f * 1.44269504088896f;  // qk scale * log2(e)

  for (int s0 = 0; s0 <= qb * 64; s0 += 64) {
    {
      int r = tid >> 2;
      int c0 = (tid & 3) * 8;
#pragma unroll
      for (int p = 0; p < 2; p++) {
        int c = c0 + p * 32;
        *(u16x8*)&Ks[r][c] = *(const u16x8*)&kp[(size_t)(s0 + r) * 64 + c];
        *(u16x8*)&VTs[r][c] = *(const u16x8*)&vp[(size_t)r * 512 + s0 + c];
      }
    }
    __syncthreads();

    // S^T tiles: kt selects 16 keys; A = K rows, B = Q^T
    f32x4 St[4];
#pragma unroll
    for (int kt = 0; kt < 4; kt++) {
      short8 a0 = *(const short8*)&Ks[kt * 16 + ln16][quad * 8];
      short8 a1 = *(const short8*)&Ks[kt * 16 + ln16][32 + quad * 8];
      f32x4 z = (f32x4){0.f, 0.f, 0.f, 0.f};
      z = __builtin_amdgcn_mfma_f32_16x16x32_bf16(a0, bq0, z, 0, 0, 0);
      z = __builtin_amdgcn_mfma_f32_16x16x32_bf16(a1, bq1, z, 0, 0, 0);
      St[kt] = z;
    }
    // scale (log2 domain) + causal mask: key = s0 + kt*16 + quad*4 + r
#pragma unroll
    for (int kt = 0; kt < 4; kt++)
#pragma unroll
      for (int r = 0; r < 4; r++) {
        int s_abs = s0 + kt * 16 + quad * 4 + r;
        float vv = St[kt][r] * SC;
        St[kt][r] = (s_abs <= t_row) ? vv : -3.0e38f;
      }
    // row max: 15 in-register + cross-quad (lanes q, q+16, q+32, q+48)
    float vm = St[0][0];
#pragma unroll
    for (int kt = 0; kt < 4; kt++)
#pragma unroll
      for (int r = 0; r < 4; r++) vm = fmaxf(vm, St[kt][r]);
    vm = fmaxf(vm, __shfl_xor(vm, 16));
    vm = fmaxf(vm, __shfl_xor(vm, 32));
    float mn = fmaxf(m_, vm);
    float alpha = exp2f(m_ - mn);
    m_ = mn;
    float ps = 0.f;
#pragma unroll
    for (int kt = 0; kt < 4; kt++)
#pragma unroll
      for (int r = 0; r < 4; r++) {
        float p = exp2f(St[kt][r] - mn);
        St[kt][r] = p;
        ps += p;
      }
    ps += __shfl_xor(ps, 16);
    ps += __shfl_xor(ps, 32);
    l_ = l_ * alpha + ps;
#pragma unroll
    for (int dt = 0; dt < 4; dt++)
#pragma unroll
      for (int r = 0; r < 4; r++) O[dt][r] *= alpha;

    // stage P^T as Pw[q][key]: 4 consecutive keys per reg quad -> b64 writes
#pragma unroll
    for (int kt = 0; kt < 4; kt++) {
      u16x4 pk = {f2bf(St[kt][0]), f2bf(St[kt][1]), f2bf(St[kt][2]), f2bf(St[kt][3])};
      *(u16x4*)&Pw[wave][ln16][kt * 16 + quad * 4] = pk;
    }
    asm volatile("" ::: "memory");  // forbid hoisting Pw reads above writes
    union { u16x8 u; short8 s; } p0, p1;
    p0.u = *(const u16x8*)&Pw[wave][ln16][quad * 8];        // keys 0..31
    p1.u = *(const u16x8*)&Pw[wave][ln16][32 + quad * 8];   // keys 32..63
#pragma unroll
    for (int dt = 0; dt < 4; dt++) {
      short8 v0 = *(const short8*)&VTs[dt * 16 + ln16][quad * 8];
      short8 v1 = *(const short8*)&VTs[dt * 16 + ln16][32 + quad * 8];
      O[dt] = __builtin_amdgcn_mfma_f32_16x16x32_bf16(v0, p0.s, O[dt], 0, 0, 0);
      O[dt] = __builtin_amdgcn_mfma_f32_16x16x32_bf16(v1, p1.s, O[dt], 0, 0, 0);
    }
    __syncthreads();
  }

  float inv = 1.0f / l_;
  int b = bh / 6, h = bh % 6;
  size_t rowbase = ((size_t)(b * 512) + t_row) * 384 + h * 64;
#pragma unroll
  for (int dt = 0; dt < 4; dt++) {
    u16x4 pk = {f2bf(O[dt][0] * inv), f2bf(O[dt][1] * inv), f2bf(O[dt][2] * inv),
                f2bf(O[dt][3] * inv)};
    *(u16x4*)&outg[rowbase + dt * 16 + quad * 4] = pk;
  }
}

// ---------------- host ----------------
extern "C" void kernel_launch(void* const* d_in, const int* in_sizes, int n_in,
                              void* d_out, int out_size, void* d_ws, size_t ws_size,
                              hipStream_t stream) {
  const float* x = (const float*)d_in[0];
  const float* Wq = (const float*)d_in[1];
  const float* Wk = (const float*)d_in[2];
  const float* Wv = (const float*)d_in[3];
  const float* Wp = (const float*)d_in[4];
  const float* bp = (const float*)d_in[5];
  const float* g1 = (const float*)d_in[6];
  const float* b1 = (const float*)d_in[7];
  const float* g2 = (const float*)d_in[8];
  const float* b2 = (const float*)d_in[9];
  const float* W1 = (const float*)d_in[10];
  const float* bf1 = (const float*)d_in[11];
  const float* W2 = (const float*)d_in[12];
  const float* bf2 = (const float*)d_in[13];
  float* outp = (float*)d_out;  // fp32 output; also hosts xr between proj and ff2

  char* ws = (char*)d_ws;
  size_t off = 0;
  auto alloc = [&](size_t elems) {
    ushort* p = (ushort*)(ws + off);
    off += elems * 2;
    return p;
  };
  ushort* WqT = alloc((size_t)384 * 384);
  ushort* WkT = alloc((size_t)384 * 384);
  ushort* WvT = alloc((size_t)384 * 384);
  ushort* WpT = alloc((size_t)384 * 384);
  ushort* W1T = alloc((size_t)384 * 1536);
  ushort* W2T = alloc((size_t)1536 * 384);
  ushort* bufq = alloc((size_t)16384 * 384);  // q, later h2
  ushort* m1 = alloc((size_t)16384 * 1536);   // [h1/attn | k | vT | spare], then ff1
  ushort* h1_attn = m1;
  ushort* bufk = m1 + (size_t)16384 * 384;
  ushort* vT = m1 + (size_t)2 * 16384 * 384;

  dim3 tb(32, 8);
  transpose_k<<<dim3(12, 12), tb, 0, stream>>>(Wq, WqT, 384, 384);
  transpose_k<<<dim3(12, 12), tb, 0, stream>>>(Wk, WkT, 384, 384);
  transpose_k<<<dim3(12, 12), tb, 0, stream>>>(Wv, WvT, 384, 384);
  transpose_k<<<dim3(12, 12), tb, 0, stream>>>(Wp, WpT, 384, 384);
  transpose_k<<<dim3(48, 12), tb, 0, stream>>>(W1, W1T, 384, 1536);
  transpose_k<<<dim3(12, 48), tb, 0, stream>>>(W2, W2T, 1536, 384);

  // h1 = ln(x, g1, b1)  [fp32 -> bf16]
  ln_k<<<4096, 256, 0, stream>>>(x, g1, b1, h1_attn);
  // q,k,vT (bf16)
  gemm_k<0, 128><<<dim3(128, 3, 3), 256, 0, stream>>>(
      h1_attn, 384, WqT, WkT, WvT, nullptr, nullptr, bufq, bufk, vT, nullptr);
  // attention -> attn (bf16, overwrites h1 slot)
  attn_k<<<dim3(8, 192), 256, 0, stream>>>(bufq, bufk, vT, h1_attn);
  // xr = attn@Wp + bp + x  (fp32, into d_out)
  gemm_k<1, 64><<<dim3(128, 6), 256, 0, stream>>>(
      h1_attn, 384, WpT, nullptr, nullptr, bp, x, nullptr, nullptr, nullptr, outp);
  // h2 = ln(xr, g2, b2)  [fp32 -> bf16, into q slot]
  ln_k<<<4096, 256, 0, stream>>>(outp, g2, b2, bufq);
  // m1 = relu(h2@W1 + bf1)  (bf16)
  gemm_k<2, 128><<<dim3(128, 12), 256, 0, stream>>>(
      bufq, 384, W1T, nullptr, nullptr, bf1, nullptr, m1, nullptr, nullptr, nullptr);
  // out = m1@W2 + bf2 + xr  (fp32, in-place on d_out)
  gemm_k<1, 64><<<dim3(128, 6), 256, 0, stream>>>(
      m1, 1536, W2T, nullptr, nullptr, bf2, outp, nullptr, nullptr, nullptr, outp);
}

// Round 6
// 280.821 us; speedup vs baseline: 1.1961x; 1.0520x over previous
//
#include <hip/hip_runtime.h>
#include <cstdint>
#include <cstddef>

#define DEVINL __device__ __forceinline__

typedef short short8 __attribute__((ext_vector_type(8)));
typedef float f32x4 __attribute__((ext_vector_type(4)));
typedef unsigned short ushort;
typedef ushort u16x8 __attribute__((ext_vector_type(8)));
typedef ushort u16x4 __attribute__((ext_vector_type(4)));

DEVINL float bf2f(ushort u) {
  union { unsigned int i; float f; } v; v.i = ((unsigned int)u) << 16; return v.f;
}
DEVINL ushort f2bf(float f) {
  union { float f; unsigned int i; } v; v.f = f;
  unsigned int u = v.i;
  unsigned int r = u + 0x7fffu + ((u >> 16) & 1u);
  return (ushort)(r >> 16);
}

// Async global->LDS, 16B per lane. LDS dest = wave-uniform base + lane*16.
DEVINL void gl2lds16(const ushort* g, ushort* l) {
  __builtin_amdgcn_global_load_lds(
      (const __attribute__((address_space(1))) void*)g,
      (__attribute__((address_space(3))) void*)l, 16, 0, 0);
}

// ------- fused 4x weight transpose + cast: f32 [384,384] -> bf16 [384,384]^T ----
__global__ void transpose4_k(const float* __restrict__ i0, const float* __restrict__ i1,
                             const float* __restrict__ i2, const float* __restrict__ i3,
                             ushort* __restrict__ o0, ushort* __restrict__ o1,
                             ushort* __restrict__ o2, ushort* __restrict__ o3) {
  __shared__ float tile[32][33];
  int z = blockIdx.z;
  const float* in = (z == 0) ? i0 : (z == 1) ? i1 : (z == 2) ? i2 : i3;
  ushort* out = (z == 0) ? o0 : (z == 1) ? o1 : (z == 2) ? o2 : o3;
  int bx = blockIdx.x, by = blockIdx.y;
  int tx = threadIdx.x, ty = threadIdx.y;  // (32,8)
  int x = bx * 32 + tx;
#pragma unroll
  for (int i = 0; i < 4; i++) {
    int y = by * 32 + ty + i * 8;
    tile[ty + i * 8][tx] = in[(size_t)y * 384 + x];
  }
  __syncthreads();
  int x2 = by * 32 + tx;
#pragma unroll
  for (int i = 0; i < 4; i++) {
    int y2 = bx * 32 + ty + i * 8;
    out[(size_t)y2 * 384 + x2] = f2bf(tile[tx][ty + i * 8]);
  }
}

// ------- generic transpose + cast: f32 [R,C] -> bf16 [C,R] ----
__global__ void transpose_k(const float* __restrict__ in, ushort* __restrict__ out,
                            int R, int C) {
  __shared__ float tile[32][33];
  int bx = blockIdx.x, by = blockIdx.y;
  int tx = threadIdx.x, ty = threadIdx.y;  // (32,8)
  int x = bx * 32 + tx;
#pragma unroll
  for (int i = 0; i < 4; i++) {
    int y = by * 32 + ty + i * 8;
    tile[ty + i * 8][tx] = in[(size_t)y * C + x];
  }
  __syncthreads();
  int x2 = by * 32 + tx;
#pragma unroll
  for (int i = 0; i < 4; i++) {
    int y2 = bx * 32 + ty + i * 8;
    out[(size_t)y2 * R + x2] = f2bf(tile[tx][ty + i * 8]);
  }
}

// ------- LayerNorm: wave per row of 384; fp32 in -> bf16 out ----
__global__ __launch_bounds__(256) void ln_k(const float* __restrict__ x,
                                            const float* __restrict__ g,
                                            const float* __restrict__ b,
                                            ushort* __restrict__ out) {
  int wave = threadIdx.x >> 6;
  int lane = threadIdx.x & 63;
  int row = blockIdx.x * 4 + wave;
  const float* xr = x + (size_t)row * 384;
  float v[6];
#pragma unroll
  for (int j = 0; j < 3; j++) {
    float2 p = *(const float2*)(xr + lane * 2 + j * 128);
    v[2 * j] = p.x;
    v[2 * j + 1] = p.y;
  }
  float s = v[0] + v[1] + v[2] + v[3] + v[4] + v[5];
#pragma unroll
  for (int off = 32; off; off >>= 1) s += __shfl_xor(s, off);
  float mu = s * (1.0f / 384.0f);
  float s2 = 0.f;
#pragma unroll
  for (int j = 0; j < 6; j++) { float d = v[j] - mu; s2 += d * d; }
#pragma unroll
  for (int off = 32; off; off >>= 1) s2 += __shfl_xor(s2, off);
  float rs = rsqrtf(s2 * (1.0f / 384.0f) + 1e-5f);
  ushort* orow = out + (size_t)row * 384;
#pragma unroll
  for (int j = 0; j < 3; j++) {
    int c = lane * 2 + j * 128;
    float2 pg = *(const float2*)(g + c);
    float2 pb = *(const float2*)(b + c);
    float y0 = (v[2 * j] - mu) * rs * pg.x + pb.x;
    float y1 = (v[2 * j + 1] - mu) * rs * pg.y + pb.y;
    uint32_t po = (uint32_t)f2bf(y0) | ((uint32_t)f2bf(y1) << 16);
    *(uint32_t*)(orow + c) = po;
  }
}

// ------- GEMM: C[M,N] = A[M,K](bf16) @ W[K,N], W as bf16 WT[N,K] ----
// Staging via global_load_lds (16B/lane, wave-uniform LDS base -> unpadded tiles)
// with XOR-4 chunk swizzle: LDS slot (row, sc) holds global chunk sc^(row&3);
// fragment reads use chunk q4^(row&3) -> bank-conflict-free b128 reads.
// MODE 0 (TN=128): QKV — grid.z selects Wq/Wk/Wv; q,k -> [B,H,T,D]; v -> [B,H,D,T]
// MODE 1 (TN=64):  outf = A@W + bias + residf (fp32 epilogue, ld 384) [proj, ff2]
// MODE 2 (TN=128): outa = bf16(relu(A@W + bias)) (ld 1536)            [ff1]
template <int MODE, int TN>
__global__ __launch_bounds__(256) void gemm_k(
    const ushort* __restrict__ A, int K,
    const ushort* __restrict__ WTa, const ushort* __restrict__ WTb,
    const ushort* __restrict__ WTc,
    const float* __restrict__ bias, const float* residf,
    ushort* __restrict__ outa, ushort* __restrict__ outb,
    ushort* __restrict__ outc, float* outf) {
  constexpr int NJ = TN / 32;  // 16-col acc tiles per wave
  __shared__ __align__(16) ushort As[128 * 32];
  __shared__ __align__(16) ushort Bs[TN * 32];
  int tid = threadIdx.x;
  int lane = tid & 63, wave = tid >> 6;
  int wm = wave & 1, wn = wave >> 1;
  int q4 = lane >> 4, ln16 = lane & 15;
  int rowBase = blockIdx.x * 128;
  int colBase = blockIdx.y * TN;

  const ushort* WT;
  if (MODE == 0) {
    int z = blockIdx.z;
    WT = (z == 0) ? WTa : (z == 1) ? WTb : WTc;
  } else {
    WT = WTa;
  }

  f32x4 acc[4][NJ];
#pragma unroll
  for (int i = 0; i < 4; i++)
#pragma unroll
    for (int j = 0; j < NJ; j++) acc[i][j] = (f32x4){0.f, 0.f, 0.f, 0.f};

  int lr = lane >> 2;                         // row within 16-row staging group
  int chunk = (lane & 3) ^ (lr & 3);          // swizzled global 8-elem chunk
  int rslot = (q4 ^ (ln16 & 3)) << 3;         // fragment read slot offset (elems)

  for (int kb = 0; kb < K; kb += 32) {
    // stage A: 128 rows x 32 k (8 KB), 2 issues/wave of 16 rows each
#pragma unroll
    for (int h = 0; h < 128; h += 64) {
      int base = wave * 16 + h;
      gl2lds16(&A[(size_t)(rowBase + base + lr) * K + kb + chunk * 8], &As[base * 32]);
    }
    // stage B: TN rows x 32 k
#pragma unroll
    for (int h = 0; h < TN; h += 64) {
      int base = wave * 16 + h;
      gl2lds16(&WT[(size_t)(colBase + base + lr) * K + kb + chunk * 8], &Bs[base * 32]);
    }
    __syncthreads();
    short8 af[4], bfr[NJ];
#pragma unroll
    for (int i = 0; i < 4; i++) {
      int ar = wm * 64 + i * 16 + ln16;
      af[i] = *(const short8*)&As[ar * 32 + rslot];
    }
#pragma unroll
    for (int j = 0; j < NJ; j++) {
      int br = wn * (TN / 2) + j * 16 + ln16;
      bfr[j] = *(const short8*)&Bs[br * 32 + rslot];
    }
#pragma unroll
    for (int i = 0; i < 4; i++)
#pragma unroll
      for (int j = 0; j < NJ; j++)
        acc[i][j] = __builtin_amdgcn_mfma_f32_16x16x32_bf16(af[i], bfr[j], acc[i][j], 0, 0, 0);
    __syncthreads();
  }

#pragma unroll
  for (int i = 0; i < 4; i++) {
#pragma unroll
    for (int j = 0; j < NJ; j++) {
      int row0 = rowBase + wm * 64 + i * 16 + q4 * 4;
      int col = colBase + wn * (TN / 2) + j * 16 + ln16;
      if (MODE == 0) {
        int z = blockIdx.z;
        if (z < 2) {
          ushort* o = (z == 0) ? outa : outb;
#pragma unroll
          for (int r = 0; r < 4; r++) {
            int row = row0 + r;
            int bb = row >> 9, t = row & 511, h = col >> 6, d = col & 63;
            o[(((size_t)(bb * 6 + h) * 512) + t) * 64 + d] = f2bf(acc[i][j][r]);
          }
        } else {
          int bb = row0 >> 9, t0 = row0 & 511, h = col >> 6, d = col & 63;
          u16x4 pk = {f2bf(acc[i][j][0]), f2bf(acc[i][j][1]), f2bf(acc[i][j][2]),
                      f2bf(acc[i][j][3])};
          *(u16x4*)&outc[(((size_t)(bb * 6 + h) * 64) + d) * 512 + t0] = pk;
        }
      } else if (MODE == 1) {
        float bcol = bias[col];
#pragma unroll
        for (int r = 0; r < 4; r++) {
          size_t idx = (size_t)(row0 + r) * 384 + col;
          outf[idx] = acc[i][j][r] + bcol + residf[idx];
        }
      } else {
        float bcol = bias[col];
#pragma unroll
        for (int r = 0; r < 4; r++) {
          size_t idx = (size_t)(row0 + r) * 1536 + col;
          float vv = acc[i][j][r] + bcol;
          outa[idx] = f2bf(vv > 0.f ? vv : 0.f);
        }
      }
    }
  }
}

// ------- flash attention, S^T formulation: wave = 16 q rows, 64-key tiles ----
// S^T = K·Q^T (C layout: col=q=lane&15, row=key) -> softmax reductions are
// in-register + 2 shuffles; O^T = V^T·P^T accumulated in C layout (col=q, row=d).
__global__ __launch_bounds__(256) void attn_k(const ushort* __restrict__ qg,
                                              const ushort* __restrict__ kg,
                                              const ushort* __restrict__ vtg,
                                              ushort* __restrict__ outg) {
  __shared__ ushort Ks[64][88];
  __shared__ ushort VTs[64][88];
  __shared__ ushort Pw[4][16][88];
  int tid = threadIdx.x, lane = tid & 63, wave = tid >> 6;
  int qb = blockIdx.x;   // 0..7
  int bh = blockIdx.y;   // 0..191
  int quad = lane >> 4, ln16 = lane & 15;
  int q0 = qb * 64 + wave * 16;
  int t_row = q0 + ln16;

  const ushort* qp = qg + (size_t)bh * 512 * 64;
  const ushort* kp = kg + (size_t)bh * 512 * 64;
  const ushort* vp = vtg + (size_t)bh * 64 * 512;

  short8 bq0 = *(const short8*)&qp[(size_t)t_row * 64 + quad * 8];
  short8 bq1 = *(const short8*)&qp[(size_t)t_row * 64 + 32 + quad * 8];

  f32x4 O[4];
#pragma unroll
  for (int dt = 0; dt < 4; dt++) O[dt] = (f32x4){0.f, 0.f, 0.f, 0.f};
  float m_ = -3.0e38f, l_ = 0.f;

  const float SC = 0.125f * 1.44269504088896f;  // qk scale * log2(e)

  for (int s0 = 0; s0 <= qb * 64; s0 += 64) {
    {
      int r = tid >> 2;
      int c0 = (tid & 3) * 8;
#pragma unroll
      for (int p = 0; p < 2; p++) {
        int c = c0 + p * 32;
        *(u16x8*)&Ks[r][c] = *(const u16x8*)&kp[(size_t)(s0 + r) * 64 + c];
        *(u16x8*)&VTs[r][c] = *(const u16x8*)&vp[(size_t)r * 512 + s0 + c];
      }
    }
    __syncthreads();

    f32x4 St[4];
#pragma unroll
    for (int kt = 0; kt < 4; kt++) {
      short8 a0 = *(const short8*)&Ks[kt * 16 + ln16][quad * 8];
      short8 a1 = *(const short8*)&Ks[kt * 16 + ln16][32 + quad * 8];
      f32x4 z = (f32x4){0.f, 0.f, 0.f, 0.f};
      z = __builtin_amdgcn_mfma_f32_16x16x32_bf16(a0, bq0, z, 0, 0, 0);
      z = __builtin_amdgcn_mfma_f32_16x16x32_bf16(a1, bq1, z, 0, 0, 0);
      St[kt] = z;
    }
#pragma unroll
    for (int kt = 0; kt < 4; kt++)
#pragma unroll
      for (int r = 0; r < 4; r++) {
        int s_abs = s0 + kt * 16 + quad * 4 + r;
        float vv = St[kt][r] * SC;
        St[kt][r] = (s_abs <= t_row) ? vv : -3.0e38f;
      }
    float vm = St[0][0];
#pragma unroll
    for (int kt = 0; kt < 4; kt++)
#pragma unroll
      for (int r = 0; r < 4; r++) vm = fmaxf(vm, St[kt][r]);
    vm = fmaxf(vm, __shfl_xor(vm, 16));
    vm = fmaxf(vm, __shfl_xor(vm, 32));
    float mn = fmaxf(m_, vm);
    float alpha = exp2f(m_ - mn);
    m_ = mn;
    float ps = 0.f;
#pragma unroll
    for (int kt = 0; kt < 4; kt++)
#pragma unroll
      for (int r = 0; r < 4; r++) {
        float p = exp2f(St[kt][r] - mn);
        St[kt][r] = p;
        ps += p;
      }
    ps += __shfl_xor(ps, 16);
    ps += __shfl_xor(ps, 32);
    l_ = l_ * alpha + ps;
#pragma unroll
    for (int dt = 0; dt < 4; dt++)
#pragma unroll
      for (int r = 0; r < 4; r++) O[dt][r] *= alpha;

#pragma unroll
    for (int kt = 0; kt < 4; kt++) {
      u16x4 pk = {f2bf(St[kt][0]), f2bf(St[kt][1]), f2bf(St[kt][2]), f2bf(St[kt][3])};
      *(u16x4*)&Pw[wave][ln16][kt * 16 + quad * 4] = pk;
    }
    asm volatile("" ::: "memory");  // forbid hoisting Pw reads above writes
    union { u16x8 u; short8 s; } p0, p1;
    p0.u = *(const u16x8*)&Pw[wave][ln16][quad * 8];
    p1.u = *(const u16x8*)&Pw[wave][ln16][32 + quad * 8];
#pragma unroll
    for (int dt = 0; dt < 4; dt++) {
      short8 v0 = *(const short8*)&VTs[dt * 16 + ln16][quad * 8];
      short8 v1 = *(const short8*)&VTs[dt * 16 + ln16][32 + quad * 8];
      O[dt] = __builtin_amdgcn_mfma_f32_16x16x32_bf16(v0, p0.s, O[dt], 0, 0, 0);
      O[dt] = __builtin_amdgcn_mfma_f32_16x16x32_bf16(v1, p1.s, O[dt], 0, 0, 0);
    }
    __syncthreads();
  }

  float inv = 1.0f / l_;
  int b = bh / 6, h = bh % 6;
  size_t rowbase = ((size_t)(b * 512) + t_row) * 384 + h * 64;
#pragma unroll
  for (int dt = 0; dt < 4; dt++) {
    u16x4 pk = {f2bf(O[dt][0] * inv), f2bf(O[dt][1] * inv), f2bf(O[dt][2] * inv),
                f2bf(O[dt][3] * inv)};
    *(u16x4*)&outg[rowbase + dt * 16 + quad * 4] = pk;
  }
}

// ---------------- host ----------------
extern "C" void kernel_launch(void* const* d_in, const int* in_sizes, int n_in,
                              void* d_out, int out_size, void* d_ws, size_t ws_size,
                              hipStream_t stream) {
  const float* x = (const float*)d_in[0];
  const float* Wq = (const float*)d_in[1];
  const float* Wk = (const float*)d_in[2];
  const float* Wv = (const float*)d_in[3];
  const float* Wp = (const float*)d_in[4];
  const float* bp = (const float*)d_in[5];
  const float* g1 = (const float*)d_in[6];
  const float* b1 = (const float*)d_in[7];
  const float* g2 = (const float*)d_in[8];
  const float* b2 = (const float*)d_in[9];
  const float* W1 = (const float*)d_in[10];
  const float* bf1 = (const float*)d_in[11];
  const float* W2 = (const float*)d_in[12];
  const float* bf2 = (const float*)d_in[13];
  float* outp = (float*)d_out;  // fp32 output; also hosts xr between proj and ff2

  char* ws = (char*)d_ws;
  size_t off = 0;
  auto alloc = [&](size_t elems) {
    ushort* p = (ushort*)(ws + off);
    off += elems * 2;
    return p;
  };
  ushort* WqT = alloc((size_t)384 * 384);
  ushort* WkT = alloc((size_t)384 * 384);
  ushort* WvT = alloc((size_t)384 * 384);
  ushort* WpT = alloc((size_t)384 * 384);
  ushort* W1T = alloc((size_t)384 * 1536);
  ushort* W2T = alloc((size_t)1536 * 384);
  ushort* bufq = alloc((size_t)16384 * 384);  // q, later h2
  ushort* m1 = alloc((size_t)16384 * 1536);   // [h1/attn | k | vT | spare], then ff1
  ushort* h1_attn = m1;
  ushort* bufk = m1 + (size_t)16384 * 384;
  ushort* vT = m1 + (size_t)2 * 16384 * 384;

  dim3 tb(32, 8);
  transpose4_k<<<dim3(12, 12, 4), tb, 0, stream>>>(Wq, Wk, Wv, Wp, WqT, WkT, WvT, WpT);
  transpose_k<<<dim3(48, 12), tb, 0, stream>>>(W1, W1T, 384, 1536);
  transpose_k<<<dim3(12, 48), tb, 0, stream>>>(W2, W2T, 1536, 384);

  // h1 = ln(x, g1, b1)  [fp32 -> bf16]
  ln_k<<<4096, 256, 0, stream>>>(x, g1, b1, h1_attn);
  // q,k,vT (bf16)
  gemm_k<0, 128><<<dim3(128, 3, 3), 256, 0, stream>>>(
      h1_attn, 384, WqT, WkT, WvT, nullptr, nullptr, bufq, bufk, vT, nullptr);
  // attention -> attn (bf16, overwrites h1 slot)
  attn_k<<<dim3(8, 192), 256, 0, stream>>>(bufq, bufk, vT, h1_attn);
  // xr = attn@Wp + bp + x  (fp32, into d_out)
  gemm_k<1, 64><<<dim3(128, 6), 256, 0, stream>>>(
      h1_attn, 384, WpT, nullptr, nullptr, bp, x, nullptr, nullptr, nullptr, outp);
  // h2 = ln(xr, g2, b2)  [fp32 -> bf16, into q slot]
  ln_k<<<4096, 256, 0, stream>>>(outp, g2, b2, bufq);
  // m1 = relu(h2@W1 + bf1)  (bf16)
  gemm_k<2, 128><<<dim3(128, 12), 256, 0, stream>>>(
      bufq, 384, W1T, nullptr, nullptr, bf1, nullptr, m1, nullptr, nullptr, nullptr);
  // out = m1@W2 + bf2 + xr  (fp32, in-place on d_out)
  gemm_k<1, 64><<<dim3(128, 6), 256, 0, stream>>>(
      m1, 1536, W2T, nullptr, nullptr, bf2, outp, nullptr, nullptr, nullptr, outp);
}

// Round 7
// 276.256 us; speedup vs baseline: 1.2158x; 1.0165x over previous
//
#include <hip/hip_runtime.h>
#include <cstdint>
#include <cstddef>

#define DEVINL __device__ __forceinline__

typedef short short8 __attribute__((ext_vector_type(8)));
typedef float f32x4 __attribute__((ext_vector_type(4)));
typedef unsigned short ushort;
typedef ushort u16x8 __attribute__((ext_vector_type(8)));
typedef ushort u16x4 __attribute__((ext_vector_type(4)));

DEVINL float bf2f(ushort u) {
  union { unsigned int i; float f; } v; v.i = ((unsigned int)u) << 16; return v.f;
}
DEVINL ushort f2bf(float f) {
  union { float f; unsigned int i; } v; v.f = f;
  unsigned int u = v.i;
  unsigned int r = u + 0x7fffu + ((u >> 16) & 1u);
  return (ushort)(r >> 16);
}

// Async global->LDS, 16B per lane. LDS dest = wave-uniform base + lane*16.
DEVINL void gl2lds16(const ushort* g, ushort* l) {
  __builtin_amdgcn_global_load_lds(
      (const __attribute__((address_space(1))) void*)g,
      (__attribute__((address_space(3))) void*)l, 16, 0, 0);
}

// ------- fused 4x weight transpose + cast: f32 [384,384] -> bf16 [384,384]^T ----
__global__ void transpose4_k(const float* __restrict__ i0, const float* __restrict__ i1,
                             const float* __restrict__ i2, const float* __restrict__ i3,
                             ushort* __restrict__ o0, ushort* __restrict__ o1,
                             ushort* __restrict__ o2, ushort* __restrict__ o3) {
  __shared__ float tile[32][33];
  int z = blockIdx.z;
  const float* in = (z == 0) ? i0 : (z == 1) ? i1 : (z == 2) ? i2 : i3;
  ushort* out = (z == 0) ? o0 : (z == 1) ? o1 : (z == 2) ? o2 : o3;
  int bx = blockIdx.x, by = blockIdx.y;
  int tx = threadIdx.x, ty = threadIdx.y;  // (32,8)
  int x = bx * 32 + tx;
#pragma unroll
  for (int i = 0; i < 4; i++) {
    int y = by * 32 + ty + i * 8;
    tile[ty + i * 8][tx] = in[(size_t)y * 384 + x];
  }
  __syncthreads();
  int x2 = by * 32 + tx;
#pragma unroll
  for (int i = 0; i < 4; i++) {
    int y2 = bx * 32 + ty + i * 8;
    out[(size_t)y2 * 384 + x2] = f2bf(tile[tx][ty + i * 8]);
  }
}

// ------- generic transpose + cast: f32 [R,C] -> bf16 [C,R] ----
__global__ void transpose_k(const float* __restrict__ in, ushort* __restrict__ out,
                            int R, int C) {
  __shared__ float tile[32][33];
  int bx = blockIdx.x, by = blockIdx.y;
  int tx = threadIdx.x, ty = threadIdx.y;  // (32,8)
  int x = bx * 32 + tx;
#pragma unroll
  for (int i = 0; i < 4; i++) {
    int y = by * 32 + ty + i * 8;
    tile[ty + i * 8][tx] = in[(size_t)y * C + x];
  }
  __syncthreads();
  int x2 = by * 32 + tx;
#pragma unroll
  for (int i = 0; i < 4; i++) {
    int y2 = bx * 32 + ty + i * 8;
    out[(size_t)y2 * R + x2] = f2bf(tile[tx][ty + i * 8]);
  }
}

// ------- LayerNorm: wave per row of 384; fp32 in -> bf16 out ----
__global__ __launch_bounds__(256) void ln_k(const float* __restrict__ x,
                                            const float* __restrict__ g,
                                            const float* __restrict__ b,
                                            ushort* __restrict__ out) {
  int wave = threadIdx.x >> 6;
  int lane = threadIdx.x & 63;
  int row = blockIdx.x * 4 + wave;
  const float* xr = x + (size_t)row * 384;
  float v[6];
#pragma unroll
  for (int j = 0; j < 3; j++) {
    float2 p = *(const float2*)(xr + lane * 2 + j * 128);
    v[2 * j] = p.x;
    v[2 * j + 1] = p.y;
  }
  float s = v[0] + v[1] + v[2] + v[3] + v[4] + v[5];
#pragma unroll
  for (int off = 32; off; off >>= 1) s += __shfl_xor(s, off);
  float mu = s * (1.0f / 384.0f);
  float s2 = 0.f;
#pragma unroll
  for (int j = 0; j < 6; j++) { float d = v[j] - mu; s2 += d * d; }
#pragma unroll
  for (int off = 32; off; off >>= 1) s2 += __shfl_xor(s2, off);
  float rs = rsqrtf(s2 * (1.0f / 384.0f) + 1e-5f);
  ushort* orow = out + (size_t)row * 384;
#pragma unroll
  for (int j = 0; j < 3; j++) {
    int c = lane * 2 + j * 128;
    float2 pg = *(const float2*)(g + c);
    float2 pb = *(const float2*)(b + c);
    float y0 = (v[2 * j] - mu) * rs * pg.x + pb.x;
    float y1 = (v[2 * j + 1] - mu) * rs * pg.y + pb.y;
    uint32_t po = (uint32_t)f2bf(y0) | ((uint32_t)f2bf(y1) << 16);
    *(uint32_t*)(orow + c) = po;
  }
}

// ------- GEMM: C[M,N] = A[M,K](bf16) @ W[K,N], W as bf16 WT[N,K] ----
// Staging via global_load_lds (16B/lane) with XOR-4 chunk swizzle.
// MODE 0 (TN=128): QKV — grid.z selects Wq/Wk/Wv; q,k -> [B,H,T,D]; v -> [B,H,D,T]
// MODE 1 (TN=64):  outf = A@W + bias + residf (fp32 epilogue, ld 384) [proj, ff2]
// MODE 2 (TN=128): outa = bf16(relu(A@W + bias)) (ld 1536)            [ff1]
template <int MODE, int TN>
__global__ __launch_bounds__(256) void gemm_k(
    const ushort* __restrict__ A, int K,
    const ushort* __restrict__ WTa, const ushort* __restrict__ WTb,
    const ushort* __restrict__ WTc,
    const float* __restrict__ bias, const float* residf,
    ushort* __restrict__ outa, ushort* __restrict__ outb,
    ushort* __restrict__ outc, float* outf) {
  constexpr int NJ = TN / 32;
  __shared__ __align__(16) ushort As[128 * 32];
  __shared__ __align__(16) ushort Bs[TN * 32];
  int tid = threadIdx.x;
  int lane = tid & 63, wave = tid >> 6;
  int wm = wave & 1, wn = wave >> 1;
  int q4 = lane >> 4, ln16 = lane & 15;
  int rowBase = blockIdx.x * 128;
  int colBase = blockIdx.y * TN;

  const ushort* WT;
  if (MODE == 0) {
    int z = blockIdx.z;
    WT = (z == 0) ? WTa : (z == 1) ? WTb : WTc;
  } else {
    WT = WTa;
  }

  f32x4 acc[4][NJ];
#pragma unroll
  for (int i = 0; i < 4; i++)
#pragma unroll
    for (int j = 0; j < NJ; j++) acc[i][j] = (f32x4){0.f, 0.f, 0.f, 0.f};

  int lr = lane >> 2;
  int chunk = (lane & 3) ^ (lr & 3);
  int rslot = (q4 ^ (ln16 & 3)) << 3;

  for (int kb = 0; kb < K; kb += 32) {
#pragma unroll
    for (int h = 0; h < 128; h += 64) {
      int base = wave * 16 + h;
      gl2lds16(&A[(size_t)(rowBase + base + lr) * K + kb + chunk * 8], &As[base * 32]);
    }
#pragma unroll
    for (int h = 0; h < TN; h += 64) {
      int base = wave * 16 + h;
      gl2lds16(&WT[(size_t)(colBase + base + lr) * K + kb + chunk * 8], &Bs[base * 32]);
    }
    __syncthreads();
    short8 af[4], bfr[NJ];
#pragma unroll
    for (int i = 0; i < 4; i++) {
      int ar = wm * 64 + i * 16 + ln16;
      af[i] = *(const short8*)&As[ar * 32 + rslot];
    }
#pragma unroll
    for (int j = 0; j < NJ; j++) {
      int br = wn * (TN / 2) + j * 16 + ln16;
      bfr[j] = *(const short8*)&Bs[br * 32 + rslot];
    }
#pragma unroll
    for (int i = 0; i < 4; i++)
#pragma unroll
      for (int j = 0; j < NJ; j++)
        acc[i][j] = __builtin_amdgcn_mfma_f32_16x16x32_bf16(af[i], bfr[j], acc[i][j], 0, 0, 0);
    __syncthreads();
  }

#pragma unroll
  for (int i = 0; i < 4; i++) {
#pragma unroll
    for (int j = 0; j < NJ; j++) {
      int row0 = rowBase + wm * 64 + i * 16 + q4 * 4;
      int col = colBase + wn * (TN / 2) + j * 16 + ln16;
      if (MODE == 0) {
        int z = blockIdx.z;
        if (z < 2) {
          ushort* o = (z == 0) ? outa : outb;
#pragma unroll
          for (int r = 0; r < 4; r++) {
            int row = row0 + r;
            int bb = row >> 9, t = row & 511, h = col >> 6, d = col & 63;
            o[(((size_t)(bb * 6 + h) * 512) + t) * 64 + d] = f2bf(acc[i][j][r]);
          }
        } else {
          int bb = row0 >> 9, t0 = row0 & 511, h = col >> 6, d = col & 63;
          u16x4 pk = {f2bf(acc[i][j][0]), f2bf(acc[i][j][1]), f2bf(acc[i][j][2]),
                      f2bf(acc[i][j][3])};
          *(u16x4*)&outc[(((size_t)(bb * 6 + h) * 64) + d) * 512 + t0] = pk;
        }
      } else if (MODE == 1) {
        float bcol = bias[col];
#pragma unroll
        for (int r = 0; r < 4; r++) {
          size_t idx = (size_t)(row0 + r) * 384 + col;
          outf[idx] = acc[i][j][r] + bcol + residf[idx];
        }
      } else {
        float bcol = bias[col];
#pragma unroll
        for (int r = 0; r < 4; r++) {
          size_t idx = (size_t)(row0 + r) * 1536 + col;
          float vv = acc[i][j][r] + bcol;
          outa[idx] = f2bf(vv > 0.f ? vv : 0.f);
        }
      }
    }
  }
}

// ------- flash attention, paired q-tiles + XCD-local bh ----
// Block handles q-tiles pr and 7-pr of one (b,h): uniform work (9 units),
// shared K/V staging. S^T = K·Q^T; softmax in-register; O^T = V^T·P^T.
// Grid: 768 1D. l&7 = XCD slot; each XCD gets 24 bh's, 4 pair-blocks each,
// consecutive (heavy pair first) -> K/V L2-resident per bh.
__global__ __launch_bounds__(256) void attn_k(const ushort* __restrict__ qg,
                                              const ushort* __restrict__ kg,
                                              const ushort* __restrict__ vtg,
                                              ushort* __restrict__ outg) {
  __shared__ ushort Ks[64][88];
  __shared__ ushort VTs[64][88];
  __shared__ ushort Pw[4][16][88];
  int tid = threadIdx.x, lane = tid & 63, wave = tid >> 6;
  int l = blockIdx.x;
  int xcd = l & 7, m = l >> 3;
  int bh = xcd * 24 + (m >> 2);
  int pr = m & 3;           // pair index: q-tiles pr (lo) and 7-pr (hi)
  int lo = pr, hi = 7 - pr;
  int quad = lane >> 4, ln16 = lane & 15;

  const ushort* qp = qg + (size_t)bh * 512 * 64;
  const ushort* kp = kg + (size_t)bh * 512 * 64;
  const ushort* vp = vtg + (size_t)bh * 64 * 512;

  int t_lo = lo * 64 + wave * 16 + ln16;
  int t_hi = hi * 64 + wave * 16 + ln16;
  short8 bqlo0 = *(const short8*)&qp[(size_t)t_lo * 64 + quad * 8];
  short8 bqlo1 = *(const short8*)&qp[(size_t)t_lo * 64 + 32 + quad * 8];
  short8 bqhi0 = *(const short8*)&qp[(size_t)t_hi * 64 + quad * 8];
  short8 bqhi1 = *(const short8*)&qp[(size_t)t_hi * 64 + 32 + quad * 8];

  f32x4 Olo[4], Ohi[4];
#pragma unroll
  for (int dt = 0; dt < 4; dt++) {
    Olo[dt] = (f32x4){0.f, 0.f, 0.f, 0.f};
    Ohi[dt] = (f32x4){0.f, 0.f, 0.f, 0.f};
  }
  float m_lo = -3.0e38f, l_lo = 0.f, m_hi = -3.0e38f, l_hi = 0.f;

  const float SC = 0.125f * 1.44269504088896f;  // qk scale * log2(e)

  auto process = [&](short8 q0f, short8 q1f, int t_row, float& m_, float& l_,
                     f32x4* O, int s0) {
    f32x4 St[4];
#pragma unroll
    for (int kt = 0; kt < 4; kt++) {
      short8 a0 = *(const short8*)&Ks[kt * 16 + ln16][quad * 8];
      short8 a1 = *(const short8*)&Ks[kt * 16 + ln16][32 + quad * 8];
      f32x4 z = (f32x4){0.f, 0.f, 0.f, 0.f};
      z = __builtin_amdgcn_mfma_f32_16x16x32_bf16(a0, q0f, z, 0, 0, 0);
      z = __builtin_amdgcn_mfma_f32_16x16x32_bf16(a1, q1f, z, 0, 0, 0);
      St[kt] = z;
    }
#pragma unroll
    for (int kt = 0; kt < 4; kt++)
#pragma unroll
      for (int r = 0; r < 4; r++) {
        int s_abs = s0 + kt * 16 + quad * 4 + r;
        float vv = St[kt][r] * SC;
        St[kt][r] = (s_abs <= t_row) ? vv : -3.0e38f;
      }
    float vm = St[0][0];
#pragma unroll
    for (int kt = 0; kt < 4; kt++)
#pragma unroll
      for (int r = 0; r < 4; r++) vm = fmaxf(vm, St[kt][r]);
    vm = fmaxf(vm, __shfl_xor(vm, 16));
    vm = fmaxf(vm, __shfl_xor(vm, 32));
    float mn = fmaxf(m_, vm);
    float alpha = exp2f(m_ - mn);
    m_ = mn;
    float ps = 0.f;
#pragma unroll
    for (int kt = 0; kt < 4; kt++)
#pragma unroll
      for (int r = 0; r < 4; r++) {
        float p = exp2f(St[kt][r] - mn);
        St[kt][r] = p;
        ps += p;
      }
    ps += __shfl_xor(ps, 16);
    ps += __shfl_xor(ps, 32);
    l_ = l_ * alpha + ps;
#pragma unroll
    for (int dt = 0; dt < 4; dt++)
#pragma unroll
      for (int r = 0; r < 4; r++) O[dt][r] *= alpha;

    asm volatile("" ::: "memory");  // order Pw writes after prior Pw reads
#pragma unroll
    for (int kt = 0; kt < 4; kt++) {
      u16x4 pk = {f2bf(St[kt][0]), f2bf(St[kt][1]), f2bf(St[kt][2]), f2bf(St[kt][3])};
      *(u16x4*)&Pw[wave][ln16][kt * 16 + quad * 4] = pk;
    }
    asm volatile("" ::: "memory");  // forbid hoisting Pw reads above writes
    union { u16x8 u; short8 s; } p0, p1;
    p0.u = *(const u16x8*)&Pw[wave][ln16][quad * 8];
    p1.u = *(const u16x8*)&Pw[wave][ln16][32 + quad * 8];
#pragma unroll
    for (int dt = 0; dt < 4; dt++) {
      short8 v0 = *(const short8*)&VTs[dt * 16 + ln16][quad * 8];
      short8 v1 = *(const short8*)&VTs[dt * 16 + ln16][32 + quad * 8];
      O[dt] = __builtin_amdgcn_mfma_f32_16x16x32_bf16(v0, p0.s, O[dt], 0, 0, 0);
      O[dt] = __builtin_amdgcn_mfma_f32_16x16x32_bf16(v1, p1.s, O[dt], 0, 0, 0);
    }
  };

  for (int s0 = 0; s0 <= hi * 64; s0 += 64) {
    {
      int r = tid >> 2;
      int c0 = (tid & 3) * 8;
#pragma unroll
      for (int p = 0; p < 2; p++) {
        int c = c0 + p * 32;
        *(u16x8*)&Ks[r][c] = *(const u16x8*)&kp[(size_t)(s0 + r) * 64 + c];
        *(u16x8*)&VTs[r][c] = *(const u16x8*)&vp[(size_t)r * 512 + s0 + c];
      }
    }
    __syncthreads();
    if (s0 <= lo * 64) process(bqlo0, bqlo1, t_lo, m_lo, l_lo, Olo, s0);
    process(bqhi0, bqhi1, t_hi, m_hi, l_hi, Ohi, s0);
    __syncthreads();
  }

  int b = bh / 6, h = bh % 6;
  float ilo = 1.0f / l_lo, ihi = 1.0f / l_hi;
  size_t base_lo = ((size_t)(b * 512) + t_lo) * 384 + h * 64;
  size_t base_hi = ((size_t)(b * 512) + t_hi) * 384 + h * 64;
#pragma unroll
  for (int dt = 0; dt < 4; dt++) {
    u16x4 plo = {f2bf(Olo[dt][0] * ilo), f2bf(Olo[dt][1] * ilo),
                 f2bf(Olo[dt][2] * ilo), f2bf(Olo[dt][3] * ilo)};
    *(u16x4*)&outg[base_lo + dt * 16 + quad * 4] = plo;
    u16x4 phi = {f2bf(Ohi[dt][0] * ihi), f2bf(Ohi[dt][1] * ihi),
                 f2bf(Ohi[dt][2] * ihi), f2bf(Ohi[dt][3] * ihi)};
    *(u16x4*)&outg[base_hi + dt * 16 + quad * 4] = phi;
  }
}

// ---------------- host ----------------
extern "C" void kernel_launch(void* const* d_in, const int* in_sizes, int n_in,
                              void* d_out, int out_size, void* d_ws, size_t ws_size,
                              hipStream_t stream) {
  const float* x = (const float*)d_in[0];
  const float* Wq = (const float*)d_in[1];
  const float* Wk = (const float*)d_in[2];
  const float* Wv = (const float*)d_in[3];
  const float* Wp = (const float*)d_in[4];
  const float* bp = (const float*)d_in[5];
  const float* g1 = (const float*)d_in[6];
  const float* b1 = (const float*)d_in[7];
  const float* g2 = (const float*)d_in[8];
  const float* b2 = (const float*)d_in[9];
  const float* W1 = (const float*)d_in[10];
  const float* bf1 = (const float*)d_in[11];
  const float* W2 = (const float*)d_in[12];
  const float* bf2 = (const float*)d_in[13];
  float* outp = (float*)d_out;  // fp32 output; also hosts xr between proj and ff2

  char* ws = (char*)d_ws;
  size_t off = 0;
  auto alloc = [&](size_t elems) {
    ushort* p = (ushort*)(ws + off);
    off += elems * 2;
    return p;
  };
  ushort* WqT = alloc((size_t)384 * 384);
  ushort* WkT = alloc((size_t)384 * 384);
  ushort* WvT = alloc((size_t)384 * 384);
  ushort* WpT = alloc((size_t)384 * 384);
  ushort* W1T = alloc((size_t)384 * 1536);
  ushort* W2T = alloc((size_t)1536 * 384);
  ushort* bufq = alloc((size_t)16384 * 384);  // q, later h2
  ushort* m1 = alloc((size_t)16384 * 1536);   // [h1/attn | k | vT | spare], then ff1
  ushort* h1_attn = m1;
  ushort* bufk = m1 + (size_t)16384 * 384;
  ushort* vT = m1 + (size_t)2 * 16384 * 384;

  dim3 tb(32, 8);
  transpose4_k<<<dim3(12, 12, 4), tb, 0, stream>>>(Wq, Wk, Wv, Wp, WqT, WkT, WvT, WpT);
  transpose_k<<<dim3(48, 12), tb, 0, stream>>>(W1, W1T, 384, 1536);
  transpose_k<<<dim3(12, 48), tb, 0, stream>>>(W2, W2T, 1536, 384);

  // h1 = ln(x, g1, b1)  [fp32 -> bf16]
  ln_k<<<4096, 256, 0, stream>>>(x, g1, b1, h1_attn);
  // q,k,vT (bf16)
  gemm_k<0, 128><<<dim3(128, 3, 3), 256, 0, stream>>>(
      h1_attn, 384, WqT, WkT, WvT, nullptr, nullptr, bufq, bufk, vT, nullptr);
  // attention -> attn (bf16, overwrites h1 slot)
  attn_k<<<768, 256, 0, stream>>>(bufq, bufk, vT, h1_attn);
  // xr = attn@Wp + bp + x  (fp32, into d_out)
  gemm_k<1, 64><<<dim3(128, 6), 256, 0, stream>>>(
      h1_attn, 384, WpT, nullptr, nullptr, bp, x, nullptr, nullptr, nullptr, outp);
  // h2 = ln(xr, g2, b2)  [fp32 -> bf16, into q slot]
  ln_k<<<4096, 256, 0, stream>>>(outp, g2, b2, bufq);
  // m1 = relu(h2@W1 + bf1)  (bf16)
  gemm_k<2, 128><<<dim3(128, 12), 256, 0, stream>>>(
      bufq, 384, W1T, nullptr, nullptr, bf1, nullptr, m1, nullptr, nullptr, nullptr);
  // out = m1@W2 + bf2 + xr  (fp32, in-place on d_out)
  gemm_k<1, 64><<<dim3(128, 6), 256, 0, stream>>>(
      m1, 1536, W2T, nullptr, nullptr, bf2, outp, nullptr, nullptr, nullptr, outp);
}

// Round 8
// 263.986 us; speedup vs baseline: 1.2723x; 1.0465x over previous
//
#include <hip/hip_runtime.h>
#include <cstdint>
#include <cstddef>

#define DEVINL __device__ __forceinline__

typedef short short8 __attribute__((ext_vector_type(8)));
typedef float f32x4 __attribute__((ext_vector_type(4)));
typedef unsigned short ushort;
typedef ushort u16x8 __attribute__((ext_vector_type(8)));
typedef ushort u16x4 __attribute__((ext_vector_type(4)));

DEVINL float bf2f(ushort u) {
  union { unsigned int i; float f; } v; v.i = ((unsigned int)u) << 16; return v.f;
}
DEVINL ushort f2bf(float f) {
  union { float f; unsigned int i; } v; v.f = f;
  unsigned int u = v.i;
  unsigned int r = u + 0x7fffu + ((u >> 16) & 1u);
  return (ushort)(r >> 16);
}

// Async global->LDS, 16B per lane. LDS dest = wave-uniform base + lane*16.
DEVINL void gl2lds16(const ushort* g, ushort* l) {
  __builtin_amdgcn_global_load_lds(
      (const __attribute__((address_space(1))) void*)g,
      (__attribute__((address_space(3))) void*)l, 16, 0, 0);
}

// ------- fused 4x weight transpose + cast: f32 [384,384] -> bf16 [384,384]^T ----
__global__ void transpose4_k(const float* __restrict__ i0, const float* __restrict__ i1,
                             const float* __restrict__ i2, const float* __restrict__ i3,
                             ushort* __restrict__ o0, ushort* __restrict__ o1,
                             ushort* __restrict__ o2, ushort* __restrict__ o3) {
  __shared__ float tile[32][33];
  int z = blockIdx.z;
  const float* in = (z == 0) ? i0 : (z == 1) ? i1 : (z == 2) ? i2 : i3;
  ushort* out = (z == 0) ? o0 : (z == 1) ? o1 : (z == 2) ? o2 : o3;
  int bx = blockIdx.x, by = blockIdx.y;
  int tx = threadIdx.x, ty = threadIdx.y;  // (32,8)
  int x = bx * 32 + tx;
#pragma unroll
  for (int i = 0; i < 4; i++) {
    int y = by * 32 + ty + i * 8;
    tile[ty + i * 8][tx] = in[(size_t)y * 384 + x];
  }
  __syncthreads();
  int x2 = by * 32 + tx;
#pragma unroll
  for (int i = 0; i < 4; i++) {
    int y2 = bx * 32 + ty + i * 8;
    out[(size_t)y2 * 384 + x2] = f2bf(tile[tx][ty + i * 8]);
  }
}

// ------- generic transpose + cast: f32 [R,C] -> bf16 [C,R] ----
__global__ void transpose_k(const float* __restrict__ in, ushort* __restrict__ out,
                            int R, int C) {
  __shared__ float tile[32][33];
  int bx = blockIdx.x, by = blockIdx.y;
  int tx = threadIdx.x, ty = threadIdx.y;  // (32,8)
  int x = bx * 32 + tx;
#pragma unroll
  for (int i = 0; i < 4; i++) {
    int y = by * 32 + ty + i * 8;
    tile[ty + i * 8][tx] = in[(size_t)y * C + x];
  }
  __syncthreads();
  int x2 = by * 32 + tx;
#pragma unroll
  for (int i = 0; i < 4; i++) {
    int y2 = bx * 32 + ty + i * 8;
    out[(size_t)y2 * R + x2] = f2bf(tile[tx][ty + i * 8]);
  }
}

// ------- LayerNorm: wave per row of 384; fp32 in -> bf16 out ----
__global__ __launch_bounds__(256) void ln_k(const float* __restrict__ x,
                                            const float* __restrict__ g,
                                            const float* __restrict__ b,
                                            ushort* __restrict__ out) {
  int wave = threadIdx.x >> 6;
  int lane = threadIdx.x & 63;
  int row = blockIdx.x * 4 + wave;
  const float* xr = x + (size_t)row * 384;
  float v[6];
#pragma unroll
  for (int j = 0; j < 3; j++) {
    float2 p = *(const float2*)(xr + lane * 2 + j * 128);
    v[2 * j] = p.x;
    v[2 * j + 1] = p.y;
  }
  float s = v[0] + v[1] + v[2] + v[3] + v[4] + v[5];
#pragma unroll
  for (int off = 32; off; off >>= 1) s += __shfl_xor(s, off);
  float mu = s * (1.0f / 384.0f);
  float s2 = 0.f;
#pragma unroll
  for (int j = 0; j < 6; j++) { float d = v[j] - mu; s2 += d * d; }
#pragma unroll
  for (int off = 32; off; off >>= 1) s2 += __shfl_xor(s2, off);
  float rs = rsqrtf(s2 * (1.0f / 384.0f) + 1e-5f);
  ushort* orow = out + (size_t)row * 384;
#pragma unroll
  for (int j = 0; j < 3; j++) {
    int c = lane * 2 + j * 128;
    float2 pg = *(const float2*)(g + c);
    float2 pb = *(const float2*)(b + c);
    float y0 = (v[2 * j] - mu) * rs * pg.x + pb.x;
    float y1 = (v[2 * j + 1] - mu) * rs * pg.y + pb.y;
    uint32_t po = (uint32_t)f2bf(y0) | ((uint32_t)f2bf(y1) << 16);
    *(uint32_t*)(orow + c) = po;
  }
}

// ------- GEMM: C[M,N] = A[M,K](bf16) @ W[K,N], W as bf16 WT[N,K] ----
// BK=64: half the barriers of BK=32, double MFMA per drain. Staging via
// global_load_lds (16B/lane, 8 rows/issue) with XOR-8 chunk swizzle:
// LDS slot s of row r holds global chunk s^(r&7); fragment reads use
// slot (ks*4+q4)^(r&7) -> minimum bank multiplicity (conflict-free b128).
// MODE 0 (TN=128): QKV — grid.z selects Wq/Wk/Wv; q,k -> [B,H,T,D]; v -> [B,H,D,T]
// MODE 1 (TN=64):  outf = A@W + bias + residf (fp32 epilogue, ld 384) [proj, ff2]
// MODE 2 (TN=128): outa = bf16(relu(A@W + bias)) (ld 1536)            [ff1]
template <int MODE, int TN>
__global__ __launch_bounds__(256) void gemm_k(
    const ushort* __restrict__ A, int K,
    const ushort* __restrict__ WTa, const ushort* __restrict__ WTb,
    const ushort* __restrict__ WTc,
    const float* __restrict__ bias, const float* residf,
    ushort* __restrict__ outa, ushort* __restrict__ outb,
    ushort* __restrict__ outc, float* outf) {
  constexpr int NJ = TN / 32;
  __shared__ __align__(16) ushort As[128 * 64];
  __shared__ __align__(16) ushort Bs[TN * 64];
  int tid = threadIdx.x;
  int lane = tid & 63, wave = tid >> 6;
  int wm = wave & 1, wn = wave >> 1;
  int q4 = lane >> 4, ln16 = lane & 15;
  int rowBase = blockIdx.x * 128;
  int colBase = blockIdx.y * TN;

  const ushort* WT;
  if (MODE == 0) {
    int z = blockIdx.z;
    WT = (z == 0) ? WTa : (z == 1) ? WTb : WTc;
  } else {
    WT = WTa;
  }

  f32x4 acc[4][NJ];
#pragma unroll
  for (int i = 0; i < 4; i++)
#pragma unroll
    for (int j = 0; j < NJ; j++) acc[i][j] = (f32x4){0.f, 0.f, 0.f, 0.f};

  int ri = lane >> 3;             // row within 8-row issue group
  int g8 = (lane & 7) ^ ri;       // swizzled global 8-elem chunk

  for (int kb = 0; kb < K; kb += 64) {
    // stage A: 128 rows x 64 k (16 KB), 4 issues/wave of 8 rows each
#pragma unroll
    for (int h = 0; h < 128; h += 32) {
      int base = h + wave * 8;
      gl2lds16(&A[(size_t)(rowBase + base + ri) * K + kb + g8 * 8], &As[base * 64]);
    }
#pragma unroll
    for (int h = 0; h < TN; h += 32) {
      int base = h + wave * 8;
      gl2lds16(&WT[(size_t)(colBase + base + ri) * K + kb + g8 * 8], &Bs[base * 64]);
    }
    __syncthreads();
#pragma unroll
    for (int ks = 0; ks < 2; ks++) {
      short8 af[4], bfr[NJ];
#pragma unroll
      for (int i = 0; i < 4; i++) {
        int ar = wm * 64 + i * 16 + ln16;
        int slot = (ks * 4 + q4) ^ (ar & 7);
        af[i] = *(const short8*)&As[ar * 64 + slot * 8];
      }
#pragma unroll
      for (int j = 0; j < NJ; j++) {
        int br = wn * (TN / 2) + j * 16 + ln16;
        int slot = (ks * 4 + q4) ^ (br & 7);
        bfr[j] = *(const short8*)&Bs[br * 64 + slot * 8];
      }
#pragma unroll
      for (int i = 0; i < 4; i++)
#pragma unroll
        for (int j = 0; j < NJ; j++)
          acc[i][j] = __builtin_amdgcn_mfma_f32_16x16x32_bf16(af[i], bfr[j], acc[i][j], 0, 0, 0);
    }
    __syncthreads();
  }

#pragma unroll
  for (int i = 0; i < 4; i++) {
#pragma unroll
    for (int j = 0; j < NJ; j++) {
      int row0 = rowBase + wm * 64 + i * 16 + q4 * 4;
      int col = colBase + wn * (TN / 2) + j * 16 + ln16;
      if (MODE == 0) {
        int z = blockIdx.z;
        if (z < 2) {
          ushort* o = (z == 0) ? outa : outb;
#pragma unroll
          for (int r = 0; r < 4; r++) {
            int row = row0 + r;
            int bb = row >> 9, t = row & 511, h = col >> 6, d = col & 63;
            o[(((size_t)(bb * 6 + h) * 512) + t) * 64 + d] = f2bf(acc[i][j][r]);
          }
        } else {
          int bb = row0 >> 9, t0 = row0 & 511, h = col >> 6, d = col & 63;
          u16x4 pk = {f2bf(acc[i][j][0]), f2bf(acc[i][j][1]), f2bf(acc[i][j][2]),
                      f2bf(acc[i][j][3])};
          *(u16x4*)&outc[(((size_t)(bb * 6 + h) * 64) + d) * 512 + t0] = pk;
        }
      } else if (MODE == 1) {
        float bcol = bias[col];
#pragma unroll
        for (int r = 0; r < 4; r++) {
          size_t idx = (size_t)(row0 + r) * 384 + col;
          outf[idx] = acc[i][j][r] + bcol + residf[idx];
        }
      } else {
        float bcol = bias[col];
#pragma unroll
        for (int r = 0; r < 4; r++) {
          size_t idx = (size_t)(row0 + r) * 1536 + col;
          float vv = acc[i][j][r] + bcol;
          outa[idx] = f2bf(vv > 0.f ? vv : 0.f);
        }
      }
    }
  }
}

// ------- flash attention, paired q-tiles + XCD-local bh ----
// Block handles q-tiles pr and 7-pr of one (b,h): uniform work (9 units),
// shared K/V staging. S^T = K·Q^T; softmax in-register; O^T = V^T·P^T.
__global__ __launch_bounds__(256) void attn_k(const ushort* __restrict__ qg,
                                              const ushort* __restrict__ kg,
                                              const ushort* __restrict__ vtg,
                                              ushort* __restrict__ outg) {
  __shared__ ushort Ks[64][88];
  __shared__ ushort VTs[64][88];
  __shared__ ushort Pw[4][16][88];
  int tid = threadIdx.x, lane = tid & 63, wave = tid >> 6;
  int l = blockIdx.x;
  int xcd = l & 7, m = l >> 3;
  int bh = xcd * 24 + (m >> 2);
  int pr = m & 3;           // pair index: q-tiles pr (lo) and 7-pr (hi)
  int lo = pr, hi = 7 - pr;
  int quad = lane >> 4, ln16 = lane & 15;

  const ushort* qp = qg + (size_t)bh * 512 * 64;
  const ushort* kp = kg + (size_t)bh * 512 * 64;
  const ushort* vp = vtg + (size_t)bh * 64 * 512;

  int t_lo = lo * 64 + wave * 16 + ln16;
  int t_hi = hi * 64 + wave * 16 + ln16;
  short8 bqlo0 = *(const short8*)&qp[(size_t)t_lo * 64 + quad * 8];
  short8 bqlo1 = *(const short8*)&qp[(size_t)t_lo * 64 + 32 + quad * 8];
  short8 bqhi0 = *(const short8*)&qp[(size_t)t_hi * 64 + quad * 8];
  short8 bqhi1 = *(const short8*)&qp[(size_t)t_hi * 64 + 32 + quad * 8];

  f32x4 Olo[4], Ohi[4];
#pragma unroll
  for (int dt = 0; dt < 4; dt++) {
    Olo[dt] = (f32x4){0.f, 0.f, 0.f, 0.f};
    Ohi[dt] = (f32x4){0.f, 0.f, 0.f, 0.f};
  }
  float m_lo = -3.0e38f, l_lo = 0.f, m_hi = -3.0e38f, l_hi = 0.f;

  const float SC = 0.125f * 1.44269504088896f;  // qk scale * log2(e)

  auto process = [&](short8 q0f, short8 q1f, int t_row, float& m_, float& l_,
                     f32x4* O, int s0) {
    f32x4 St[4];
#pragma unroll
    for (int kt = 0; kt < 4; kt++) {
      short8 a0 = *(const short8*)&Ks[kt * 16 + ln16][quad * 8];
      short8 a1 = *(const short8*)&Ks[kt * 16 + ln16][32 + quad * 8];
      f32x4 z = (f32x4){0.f, 0.f, 0.f, 0.f};
      z = __builtin_amdgcn_mfma_f32_16x16x32_bf16(a0, q0f, z, 0, 0, 0);
      z = __builtin_amdgcn_mfma_f32_16x16x32_bf16(a1, q1f, z, 0, 0, 0);
      St[kt] = z;
    }
#pragma unroll
    for (int kt = 0; kt < 4; kt++)
#pragma unroll
      for (int r = 0; r < 4; r++) {
        int s_abs = s0 + kt * 16 + quad * 4 + r;
        float vv = St[kt][r] * SC;
        St[kt][r] = (s_abs <= t_row) ? vv : -3.0e38f;
      }
    float vm = St[0][0];
#pragma unroll
    for (int kt = 0; kt < 4; kt++)
#pragma unroll
      for (int r = 0; r < 4; r++) vm = fmaxf(vm, St[kt][r]);
    vm = fmaxf(vm, __shfl_xor(vm, 16));
    vm = fmaxf(vm, __shfl_xor(vm, 32));
    float mn = fmaxf(m_, vm);
    float alpha = exp2f(m_ - mn);
    m_ = mn;
    float ps = 0.f;
#pragma unroll
    for (int kt = 0; kt < 4; kt++)
#pragma unroll
      for (int r = 0; r < 4; r++) {
        float p = exp2f(St[kt][r] - mn);
        St[kt][r] = p;
        ps += p;
      }
    ps += __shfl_xor(ps, 16);
    ps += __shfl_xor(ps, 32);
    l_ = l_ * alpha + ps;
#pragma unroll
    for (int dt = 0; dt < 4; dt++)
#pragma unroll
      for (int r = 0; r < 4; r++) O[dt][r] *= alpha;

    asm volatile("" ::: "memory");  // order Pw writes after prior Pw reads
#pragma unroll
    for (int kt = 0; kt < 4; kt++) {
      u16x4 pk = {f2bf(St[kt][0]), f2bf(St[kt][1]), f2bf(St[kt][2]), f2bf(St[kt][3])};
      *(u16x4*)&Pw[wave][ln16][kt * 16 + quad * 4] = pk;
    }
    asm volatile("" ::: "memory");  // forbid hoisting Pw reads above writes
    union { u16x8 u; short8 s; } p0, p1;
    p0.u = *(const u16x8*)&Pw[wave][ln16][quad * 8];
    p1.u = *(const u16x8*)&Pw[wave][ln16][32 + quad * 8];
#pragma unroll
    for (int dt = 0; dt < 4; dt++) {
      short8 v0 = *(const short8*)&VTs[dt * 16 + ln16][quad * 8];
      short8 v1 = *(const short8*)&VTs[dt * 16 + ln16][32 + quad * 8];
      O[dt] = __builtin_amdgcn_mfma_f32_16x16x32_bf16(v0, p0.s, O[dt], 0, 0, 0);
      O[dt] = __builtin_amdgcn_mfma_f32_16x16x32_bf16(v1, p1.s, O[dt], 0, 0, 0);
    }
  };

  for (int s0 = 0; s0 <= hi * 64; s0 += 64) {
    {
      int r = tid >> 2;
      int c0 = (tid & 3) * 8;
#pragma unroll
      for (int p = 0; p < 2; p++) {
        int c = c0 + p * 32;
        *(u16x8*)&Ks[r][c] = *(const u16x8*)&kp[(size_t)(s0 + r) * 64 + c];
        *(u16x8*)&VTs[r][c] = *(const u16x8*)&vp[(size_t)r * 512 + s0 + c];
      }
    }
    __syncthreads();
    if (s0 <= lo * 64) process(bqlo0, bqlo1, t_lo, m_lo, l_lo, Olo, s0);
    process(bqhi0, bqhi1, t_hi, m_hi, l_hi, Ohi, s0);
    __syncthreads();
  }

  int b = bh / 6, h = bh % 6;
  float ilo = 1.0f / l_lo, ihi = 1.0f / l_hi;
  size_t base_lo = ((size_t)(b * 512) + t_lo) * 384 + h * 64;
  size_t base_hi = ((size_t)(b * 512) + t_hi) * 384 + h * 64;
#pragma unroll
  for (int dt = 0; dt < 4; dt++) {
    u16x4 plo = {f2bf(Olo[dt][0] * ilo), f2bf(Olo[dt][1] * ilo),
                 f2bf(Olo[dt][2] * ilo), f2bf(Olo[dt][3] * ilo)};
    *(u16x4*)&outg[base_lo + dt * 16 + quad * 4] = plo;
    u16x4 phi = {f2bf(Ohi[dt][0] * ihi), f2bf(Ohi[dt][1] * ihi),
                 f2bf(Ohi[dt][2] * ihi), f2bf(Ohi[dt][3] * ihi)};
    *(u16x4*)&outg[base_hi + dt * 16 + quad * 4] = phi;
  }
}

// ---------------- host ----------------
extern "C" void kernel_launch(void* const* d_in, const int* in_sizes, int n_in,
                              void* d_out, int out_size, void* d_ws, size_t ws_size,
                              hipStream_t stream) {
  const float* x = (const float*)d_in[0];
  const float* Wq = (const float*)d_in[1];
  const float* Wk = (const float*)d_in[2];
  const float* Wv = (const float*)d_in[3];
  const float* Wp = (const float*)d_in[4];
  const float* bp = (const float*)d_in[5];
  const float* g1 = (const float*)d_in[6];
  const float* b1 = (const float*)d_in[7];
  const float* g2 = (const float*)d_in[8];
  const float* b2 = (const float*)d_in[9];
  const float* W1 = (const float*)d_in[10];
  const float* bf1 = (const float*)d_in[11];
  const float* W2 = (const float*)d_in[12];
  const float* bf2 = (const float*)d_in[13];
  float* outp = (float*)d_out;  // fp32 output; also hosts xr between proj and ff2

  char* ws = (char*)d_ws;
  size_t off = 0;
  auto alloc = [&](size_t elems) {
    ushort* p = (ushort*)(ws + off);
    off += elems * 2;
    return p;
  };
  ushort* WqT = alloc((size_t)384 * 384);
  ushort* WkT = alloc((size_t)384 * 384);
  ushort* WvT = alloc((size_t)384 * 384);
  ushort* WpT = alloc((size_t)384 * 384);
  ushort* W1T = alloc((size_t)384 * 1536);
  ushort* W2T = alloc((size_t)1536 * 384);
  ushort* bufq = alloc((size_t)16384 * 384);  // q, later h2
  ushort* m1 = alloc((size_t)16384 * 1536);   // [h1/attn | k | vT | spare], then ff1
  ushort* h1_attn = m1;
  ushort* bufk = m1 + (size_t)16384 * 384;
  ushort* vT = m1 + (size_t)2 * 16384 * 384;

  dim3 tb(32, 8);
  transpose4_k<<<dim3(12, 12, 4), tb, 0, stream>>>(Wq, Wk, Wv, Wp, WqT, WkT, WvT, WpT);
  transpose_k<<<dim3(48, 12), tb, 0, stream>>>(W1, W1T, 384, 1536);
  transpose_k<<<dim3(12, 48), tb, 0, stream>>>(W2, W2T, 1536, 384);

  // h1 = ln(x, g1, b1)  [fp32 -> bf16]
  ln_k<<<4096, 256, 0, stream>>>(x, g1, b1, h1_attn);
  // q,k,vT (bf16)
  gemm_k<0, 128><<<dim3(128, 3, 3), 256, 0, stream>>>(
      h1_attn, 384, WqT, WkT, WvT, nullptr, nullptr, bufq, bufk, vT, nullptr);
  // attention -> attn (bf16, overwrites h1 slot)
  attn_k<<<768, 256, 0, stream>>>(bufq, bufk, vT, h1_attn);
  // xr = attn@Wp + bp + x  (fp32, into d_out)
  gemm_k<1, 64><<<dim3(128, 6), 256, 0, stream>>>(
      h1_attn, 384, WpT, nullptr, nullptr, bp, x, nullptr, nullptr, nullptr, outp);
  // h2 = ln(xr, g2, b2)  [fp32 -> bf16, into q slot]
  ln_k<<<4096, 256, 0, stream>>>(outp, g2, b2, bufq);
  // m1 = relu(h2@W1 + bf1)  (bf16)
  gemm_k<2, 128><<<dim3(128, 12), 256, 0, stream>>>(
      bufq, 384, W1T, nullptr, nullptr, bf1, nullptr, m1, nullptr, nullptr, nullptr);
  // out = m1@W2 + bf2 + xr  (fp32, in-place on d_out)
  gemm_k<1, 64><<<dim3(128, 6), 256, 0, stream>>>(
      m1, 1536, W2T, nullptr, nullptr, bf2, outp, nullptr, nullptr, nullptr, outp);
}